// Round 18
// baseline (795.227 us; speedup 1.0000x reference)
//
#include <hip/hip_runtime.h>
#include <hip/hip_bf16.h>
#include <math.h>
#include <cstdint>

static constexpr int NN = 50000;   // nodes
static constexpr int NE = 400000;  // edges
static constexpr int H  = 400;     // hidden dim
static constexpr int NG = 128;     // graphs
static constexpr int NC = 10;      // classes
static constexpr float EPS = 1e-5f;
static constexpr int NB1 = (NN + 255) / 256;   // 196 scan blocks
static constexpr int KP  = 416;                // padded K for weights
static constexpr int SREP = 8;                 // stats replicas (contention spread)
static constexpr int SSLOT = SREP * 2 * KP;    // floats per stats slot

typedef unsigned short u16;
typedef __attribute__((ext_vector_type(8))) unsigned short u16x8;
typedef __attribute__((ext_vector_type(4))) unsigned short u16x4;
typedef __attribute__((ext_vector_type(8))) short bf16x8;
typedef __attribute__((ext_vector_type(4))) float f32x4;

__device__ __forceinline__ float bf2f(u16 u) {
    return __uint_as_float(((uint32_t)u) << 16);
}
__device__ __forceinline__ u16 f2bf(float f) {
    uint32_t u = __float_as_uint(f);
    return (u16)((u + 0x7FFFu + ((u >> 16) & 1u)) >> 16);
}
__device__ __forceinline__ void gload_lds16(const void* g, void* lds) {
    __builtin_amdgcn_global_load_lds((const __attribute__((address_space(1))) void*)g,
                                     (__attribute__((address_space(3))) void*)lds, 16, 0, 0);
}

// BN+ReLU on a bf16x8 fragment using HW packed bf16 convert
__device__ __forceinline__ bf16x8 bnrelu8(bf16x8 a, const float* __restrict__ scp,
                                          const float* __restrict__ shp) {
    union { bf16x8 v; uint32_t u[4]; } in, out;
    in.v = a;
#pragma unroll
    for (int p = 0; p < 4; ++p) {
        float lo = __uint_as_float(in.u[p] << 16);
        float hi = __uint_as_float(in.u[p] & 0xFFFF0000u);
        lo = fmaxf(fmaf(lo, scp[2 * p], shp[2 * p]), 0.f);
        hi = fmaxf(fmaf(hi, scp[2 * p + 1], shp[2 * p + 1]), 0.f);
        asm("v_cvt_pk_bf16_f32 %0, %1, %2" : "=v"(out.u[p]) : "v"(lo), "v"(hi));
    }
    return out.v;
}

// ---------------- CSR build ----------------

__global__ void k_count(const int* __restrict__ dst, int* __restrict__ deg) {
    int e = blockIdx.x * blockDim.x + threadIdx.x;
    if (e < NE) atomicAdd(&deg[dst[e]], 1);
}

__global__ __launch_bounds__(256) void k_scan1(const int* __restrict__ deg,
                                               int* __restrict__ part,
                                               int* __restrict__ btot) {
    __shared__ int sd[256];
    int t = threadIdx.x;
    int i = blockIdx.x * 256 + t;
    int v = (i < NN) ? deg[i] : 0;
    sd[t] = v;
    __syncthreads();
#pragma unroll
    for (int off = 1; off < 256; off <<= 1) {
        int x = (t >= off) ? sd[t - off] : 0;
        __syncthreads();
        sd[t] += x;
        __syncthreads();
    }
    if (i < NN) part[i] = sd[t];
    if (t == 255) btot[blockIdx.x] = sd[255];
}

__global__ __launch_bounds__(256) void k_scan2(int* __restrict__ btot) {
    __shared__ int sd[256];
    int t = threadIdx.x;
    int v = (t < NB1) ? btot[t] : 0;
    sd[t] = v;
    __syncthreads();
#pragma unroll
    for (int off = 1; off < 256; off <<= 1) {
        int x = (t >= off) ? sd[t - off] : 0;
        __syncthreads();
        sd[t] += x;
        __syncthreads();
    }
    if (t < NB1) btot[t] = sd[t];
}

// scan3 + graph-count fused
__global__ __launch_bounds__(256) void k_scan3(const int* __restrict__ part,
                                               const int* __restrict__ btot,
                                               const int* __restrict__ deg,
                                               int* __restrict__ rowp,
                                               int* __restrict__ cur,
                                               const int* __restrict__ batch,
                                               int* __restrict__ cnt) {
    __shared__ int hh[NG];
    int t = threadIdx.x;
    int i = blockIdx.x * 256 + t;
    if (i < NN) {
        int s = part[i] + (blockIdx.x ? btot[blockIdx.x - 1] : 0);
        rowp[i + 1] = s;
        cur[i] = s - deg[i];
    }
    if (i == 0) rowp[0] = 0;
    for (int j = t; j < NG; j += 256) hh[j] = 0;
    __syncthreads();
    if (i < NN) atomicAdd(&hh[batch[i]], 1);
    __syncthreads();
    for (int j = t; j < NG; j += 256)
        if (hh[j]) atomicAdd(&cnt[j], hh[j]);
}

__global__ void k_scatter(const int* __restrict__ src, const int* __restrict__ dst,
                          int* __restrict__ cur, int* __restrict__ csrc) {
    int e = blockIdx.x * blockDim.x + threadIdx.x;
    if (e < NE) {
        int d = dst[e];
        int p = atomicAdd(&cur[d], 1);
        csrc[p] = src[e];
    }
}

// ---------------- unified weight prep (flat grid) ----------------

__global__ __launch_bounds__(256) void k_wprep(const float* __restrict__ c0_w2,
                                               const float* __restrict__ cw2,
                                               const float* __restrict__ cw1,
                                               const float* __restrict__ c0_w3,
                                               const float* __restrict__ cw3,
                                               const float* __restrict__ c0_b3,
                                               const float* __restrict__ cb3,
                                               u16* __restrict__ wpad,
                                               float* __restrict__ bb1,
                                               float* __restrict__ bb2) {
    const int b = blockIdx.x;
    const int t = threadIdx.x;
    if (b < 244) {
        int i = b * 256 + t;
        if (i >= 3 * 400 * 52) return;
        int rc = i / 52;
        int c8 = (i % 52) * 8;
        u16x8 o = {0, 0, 0, 0, 0, 0, 0, 0};
        if (c8 < 400) {
            int mat = rc / 400, row = rc % 400;
            const float* s = (mat == 0 ? c0_w2 : mat == 1 ? cw2 : cw2 + 160000)
                             + (long)row * 400;
            float4 a = *(const float4*)(s + c8);
            float4 bb = *(const float4*)(s + c8 + 4);
            o[0] = f2bf(a.x); o[1] = f2bf(a.y); o[2] = f2bf(a.z); o[3] = f2bf(a.w);
            o[4] = f2bf(bb.x); o[5] = f2bf(bb.y); o[6] = f2bf(bb.z); o[7] = f2bf(bb.w);
        }
        *(u16x8*)(wpad + (long)rc * KP + c8) = o;
    } else if (b < 342) {
        __shared__ float As[16][68];
        __shared__ float Bs[16][68];
        const int b2 = (b < 293) ? b - 244 : b - 293;
        const float* Wa = (b < 293) ? cw1 : cw1 + 160000;
        const float* Wb = (b < 293) ? c0_w3 : cw3;
        u16* dst = wpad + (size_t)((b < 293) ? 3 : 4) * 400 * KP;
        const int bc = (b2 / 7) * 64, bj = (b2 % 7) * 64;
        const int tx = t & 15, ty = t >> 4;
        float acc[4][4] = {};
        for (int k0 = 0; k0 < 400; k0 += 16) {
            {
                int c = bc + (t >> 2);
                int kq = (t & 3) * 4;
                float4 v = make_float4(0.f, 0.f, 0.f, 0.f);
                if (c < 400) v = *(const float4*)(Wa + (long)c * 400 + k0 + kq);
                As[kq + 0][t >> 2] = v.x; As[kq + 1][t >> 2] = v.y;
                As[kq + 2][t >> 2] = v.z; As[kq + 3][t >> 2] = v.w;
            }
            {
                int k = k0 + (t >> 4);
                int jq = (t & 15) * 4;
                int j = bj + jq;
                float4 v = make_float4(0.f, 0.f, 0.f, 0.f);
                if (j < 400) v = *(const float4*)(Wb + (long)k * 400 + j);
                Bs[t >> 4][jq + 0] = v.x; Bs[t >> 4][jq + 1] = v.y;
                Bs[t >> 4][jq + 2] = v.z; Bs[t >> 4][jq + 3] = v.w;
            }
            __syncthreads();
#pragma unroll
            for (int kk = 0; kk < 16; ++kk) {
                float4 av = *(const float4*)&As[kk][ty * 4];
                float4 bv = *(const float4*)&Bs[kk][tx * 4];
                float a[4] = {av.x, av.y, av.z, av.w};
                float bb[4] = {bv.x, bv.y, bv.z, bv.w};
#pragma unroll
                for (int i = 0; i < 4; ++i)
#pragma unroll
                    for (int j = 0; j < 4; ++j)
                        acc[i][j] = fmaf(a[i], bb[j], acc[i][j]);
            }
            __syncthreads();
        }
#pragma unroll
        for (int i = 0; i < 4; ++i) {
            int c = bc + ty * 4 + i;
            if (c >= 400) continue;
#pragma unroll
            for (int j = 0; j < 4; ++j) {
                int col = bj + tx * 4 + j;
                if (col < KP) dst[(long)c * KP + col] = (col < 400) ? f2bf(acc[i][j]) : 0;
            }
        }
    } else {
        const int c = (b & 1) * 256 + t;
        if (c >= 400) return;
        const float* Wa = (b < 344) ? cw1 : cw1 + 160000;
        const float* bv = (b < 344) ? c0_b3 : cb3;
        float* out = (b < 344) ? bb1 : bb2;
        const float4* wr = (const float4*)(Wa + (long)c * 400);
        const float4* br = (const float4*)bv;
        float s0 = 0.f, s1 = 0.f, s2 = 0.f, s3 = 0.f;
        for (int q = 0; q < 100; ++q) {
            float4 a = wr[q], v = br[q];
            s0 = fmaf(a.x, v.x, s0); s1 = fmaf(a.y, v.y, s1);
            s2 = fmaf(a.z, v.z, s2); s3 = fmaf(a.w, v.w, s3);
        }
        out[c] = s0 + s1 + s2 + s3;
    }
}

// ---------------- agg0 + moments ----------------

__global__ __launch_bounds__(256) void k_agg0(const float* __restrict__ x,
                                              const int* __restrict__ rowp,
                                              const int* __restrict__ csrc,
                                              float* __restrict__ out,
                                              float* __restrict__ mom) {
    __shared__ float ws[4][14];
    int n = blockIdx.x * blockDim.x + threadIdx.x;
    float4 acc = make_float4(0.f, 0.f, 0.f, 0.f);
    if (n < NN) {
        int b = rowp[n], e = rowp[n + 1];
        for (int p = b; p < e; ++p) {
            float4 v = ((const float4*)x)[csrc[p]];
            acc.x += v.x; acc.y += v.y; acc.z += v.z; acc.w += v.w;
        }
        ((float4*)out)[n] = acc;
    }
    float mv[14] = {acc.x, acc.y, acc.z, acc.w,
                    acc.x * acc.x, acc.x * acc.y, acc.x * acc.z, acc.x * acc.w,
                    acc.y * acc.y, acc.y * acc.z, acc.y * acc.w,
                    acc.z * acc.z, acc.z * acc.w, acc.w * acc.w};
    int wv = threadIdx.x >> 6, l = threadIdx.x & 63;
#pragma unroll
    for (int i = 0; i < 14; ++i) {
        float s = mv[i];
#pragma unroll
        for (int o = 32; o; o >>= 1) s += __shfl_xor(s, o);
        if (l == 0) ws[wv][i] = s;
    }
    __syncthreads();
    if (threadIdx.x < 14) {
        float s = ws[0][threadIdx.x] + ws[1][threadIdx.x] + ws[2][threadIdx.x] + ws[3][threadIdx.x];
        atomicAdd(&mom[threadIdx.x], s);
    }
}

// ---------------- aggH: one wave per node ----------------

__global__ __launch_bounds__(256) void k_aggH(const u16* __restrict__ h,
                                              const int* __restrict__ rowp,
                                              const int* __restrict__ csrc,
                                              const float* __restrict__ bias,
                                              u16* __restrict__ out) {
    int n = (blockIdx.x << 2) + (threadIdx.x >> 6);
    if (n >= NN) return;
    int l = threadIdx.x & 63;
    if (l >= 50) return;
    float4 b0 = *(const float4*)(bias + l * 8);
    float4 b1 = *(const float4*)(bias + l * 8 + 4);
    float acc[8] = {b0.x, b0.y, b0.z, b0.w, b1.x, b1.y, b1.z, b1.w};
    int b = rowp[n], e = rowp[n + 1];
    for (int p = b; p < e; ++p) {
        const u16* r = h + (long)csrc[p] * H + l * 8;
        u16x8 v = *(const u16x8*)r;
#pragma unroll
        for (int q = 0; q < 8; ++q) acc[q] += bf2f(v[q]);
    }
    u16x8 o;
#pragma unroll
    for (int q = 0; q < 8; ++q) o[q] = f2bf(acc[q]);
    *(u16x8*)(out + (long)n * H + l * 8) = o;
}

// ---------------- first linear (K = 4) + fused analytic z1 stats ----------------

static constexpr int NLIN0 = (int)(((long)NN * 100 + 255) / 256);

__global__ void k_lin0(const float* __restrict__ a4, const float* __restrict__ w,
                       const float* __restrict__ b, u16* __restrict__ out,
                       const float* __restrict__ mom, float* __restrict__ slot0) {
    if (blockIdx.x >= NLIN0) {
        int j = (blockIdx.x - NLIN0) * 256 + threadIdx.x;
        if (j >= 400) return;
        float4 wv = ((const float4*)w)[j];
        float dot = wv.x * mom[0] + wv.y * mom[1] + wv.z * mom[2] + wv.w * mom[3];
        float quad = wv.x * wv.x * mom[4] + 2.f * wv.x * wv.y * mom[5]
                   + 2.f * wv.x * wv.z * mom[6] + 2.f * wv.x * wv.w * mom[7]
                   + wv.y * wv.y * mom[8] + 2.f * wv.y * wv.z * mom[9]
                   + 2.f * wv.y * wv.w * mom[10] + wv.z * wv.z * mom[11]
                   + 2.f * wv.z * wv.w * mom[12] + wv.w * wv.w * mom[13];
        float bj = b[j];
        slot0[j] = dot + (float)NN * bj;
        slot0[KP + j] = quad + 2.f * bj * dot + (float)NN * bj * bj;
        return;
    }
    long i = (long)blockIdx.x * blockDim.x + threadIdx.x;
    if (i >= (long)NN * 100) return;
    int n = (int)(i / 100), q = (int)(i - (long)n * 100);
    int j0 = q * 4;
    float4 av = ((const float4*)a4)[n];
    u16x4 o;
#pragma unroll
    for (int jj = 0; jj < 4; ++jj) {
        float4 wv = ((const float4*)w)[j0 + jj];
        float s = fmaf(av.x, wv.x, fmaf(av.y, wv.y, fmaf(av.z, wv.z, av.w * wv.w)));
        o[jj] = f2bf(s + b[j0 + jj]);
    }
    *(u16x4*)(out + (long)n * H + j0) = o;
}

// ---------------- BN stats over bf16 buffer -> replica slot ----------------

__global__ __launch_bounds__(256) void k_statsv(const u16* __restrict__ z,
                                                float* __restrict__ stats) {
    __shared__ float ls[800];
    int t = threadIdx.x;
    for (int i = t; i < 800; i += 256) ls[i] = 0.f;
    __syncthreads();
    if (t < 250) {
        int sub = t / 50, seg = t % 50;
        float s[8] = {0, 0, 0, 0, 0, 0, 0, 0};
        float q[8] = {0, 0, 0, 0, 0, 0, 0, 0};
        for (int r = blockIdx.x * 5 + sub; r < NN; r += gridDim.x * 5) {
            u16x8 v = *(const u16x8*)(z + (long)r * H + seg * 8);
#pragma unroll
            for (int j = 0; j < 8; ++j) {
                float f = bf2f(v[j]);
                s[j] += f; q[j] += f * f;
            }
        }
#pragma unroll
        for (int j = 0; j < 8; ++j) {
            atomicAdd(&ls[seg * 8 + j], s[j]);
            atomicAdd(&ls[400 + seg * 8 + j], q[j]);
        }
    }
    __syncthreads();
    const int rep = blockIdx.x & (SREP - 1);
    for (int i = t; i < 800; i += 256) {
        int col = (i < 400) ? i : (i - 400 + KP);
        atomicAdd(&stats[rep * 2 * KP + col], ls[i]);
    }
}

// ---------------- MFMA GEMM: barrier-free K-loop ----------------
// 512 threads (8 waves), tile 256x80, B resident in LDS (80x416, granule-XOR),
// A staged per-wave into private LDS buffers via gload_lds (4 buffers, 3-deep
// prefetch, per-wave vmcnt). ONE barrier after B-stage; waves free-run the
// 13-step K-loop with zero inter-wave sync. Fused BN-finalize + BN/ReLU + stats.

template <bool STATS>
__global__ __launch_bounds__(512, 1) void gemm_mfma(const u16* __restrict__ A,
                                                    const u16* __restrict__ Wp,
                                                    const float* __restrict__ bias,
                                                    const float* __restrict__ bnG,
                                                    const float* __restrict__ bnBe,
                                                    const float* __restrict__ statsIn,
                                                    float* __restrict__ statsOut,
                                                    u16* __restrict__ out, int M) {
    // lds: Bs [80*416] | As [8 waves][4 buf][2 seg][512]
    __shared__ u16 lds[33280 + 8 * 4 * 2 * 512];   // 132,096 B
    __shared__ float sdScale[KP];
    __shared__ float sdShift[KP];
    __shared__ float sst[160];

    const int t = threadIdx.x;
    const int nwg = gridDim.x;                      // 980: bijective XCD swizzle
    const int q8 = nwg >> 3, r8 = nwg & 7;
    const int xcd = blockIdx.x & 7, jj = blockIdx.x >> 3;
    const int wgid = (xcd < r8 ? xcd * (q8 + 1) : r8 * (q8 + 1) + (xcd - r8) * q8) + jj;
    const int bm = (wgid / 5) * 256;
    const int bn = (wgid % 5) * 80;
    const int w = t >> 6, l = t & 63;

    u16* Bs = lds;
    u16* Aw = lds + 33280 + w * 4096;               // this wave's 4x2x512

    // ---- A prologue: tiles 0,1,2 into private buffers (per-wave gload) ----
    const int srow = l >> 2;
    const int sck  = ((l & 3) ^ ((l >> 3) & 3)) * 8;   // source-side XOR swizzle
    long gr0 = (long)bm + w * 32 + srow;
    long gr1 = gr0 + 16;
    if (gr0 > M - 1) gr0 = M - 1;
    if (gr1 > M - 1) gr1 = M - 1;
    const u16* pA0 = A + gr0 * 400 + sck;
    const u16* pA1 = A + gr1 * 400 + sck;
#pragma unroll
    for (int kt = 0; kt < 3; ++kt) {
        gload_lds16(pA0 + kt * 32, Aw + (kt * 2 + 0) * 512);
        gload_lds16(pA1 + kt * 32, Aw + (kt * 2 + 1) * 512);
    }

    // ---- B stage (write-side granule XOR) ----
    for (int i = t; i < 80 * 52; i += 512) {
        int row = i / 52, g = i % 52;
        u16x8 v = *(const u16x8*)(Wp + (long)(bn + row) * KP + g * 8);
        int pg = (g & ~3) | ((g & 3) ^ ((row >> 1) & 3));
        *(u16x8*)&Bs[row * 416 + pg * 8] = v;
    }

    // ---- BN finalize prologue ----
    for (int j = t; j < KP; j += 512) {
        float s = 0.f, q = 0.f;
#pragma unroll
        for (int r = 0; r < SREP; ++r) {
            s += statsIn[r * 2 * KP + j];
            q += statsIn[r * 2 * KP + KP + j];
        }
        float sc = 0.f, sh = 0.f;
        if (j < H) {
            float m = s / NN;
            float v = fmaxf(q / NN - m * m, 0.f);
            float rs = rsqrtf(v + EPS);
            sc = bnG[j] * rs;
            sh = bnBe[j] - m * sc;
        }
        sdScale[j] = sc;
        sdShift[j] = sh;
    }
    __syncthreads();                                // the ONE pre-epilogue barrier

    f32x4 acc[2][5];
#pragma unroll
    for (int i = 0; i < 2; ++i)
#pragma unroll
        for (int c = 0; c < 5; ++c)
            acc[i][c] = (f32x4){0.f, 0.f, 0.f, 0.f};

    const int r16 = l & 15;
    const int cc  = l >> 4;
    const int swzA = r16 * 32 + ((cc ^ ((r16 >> 1) & 3)) << 3);
    const int swzB = (cc ^ ((r16 >> 1) & 3)) << 3;

    auto computeTile = [&](int s) {
        const u16* ab = Aw + ((s & 3) * 2) * 512 + swzA;
        bf16x8 fa0 = *(const bf16x8*)ab;
        bf16x8 fa1 = *(const bf16x8*)(ab + 512);
        const int k = s * 32 + cc * 8;
        fa0 = bnrelu8(fa0, sdScale + k, sdShift + k);
        fa1 = bnrelu8(fa1, sdScale + k, sdShift + k);
        const u16* bb = Bs + r16 * 416 + s * 32 + swzB;
        __builtin_amdgcn_s_setprio(1);
#pragma unroll
        for (int c = 0; c < 5; ++c) {
            bf16x8 fb = *(const bf16x8*)(bb + c * 16 * 416);
            acc[0][c] = __builtin_amdgcn_mfma_f32_16x16x32_bf16(fa0, fb, acc[0][c], 0, 0, 0);
            acc[1][c] = __builtin_amdgcn_mfma_f32_16x16x32_bf16(fa1, fb, acc[1][c], 0, 0, 0);
        }
        __builtin_amdgcn_s_setprio(0);
    };

    // ---- barrier-free K-loop: per-wave counted vmcnt, 3-deep prefetch ----
#pragma unroll 1
    for (int s = 0; s < 11; ++s) {
        asm volatile("s_waitcnt vmcnt(4)" ::: "memory");   // own tile-s loads done
        __builtin_amdgcn_sched_barrier(0);
        if (s < 10) {
            const int kt = s + 3;
            gload_lds16(pA0 + kt * 32, Aw + ((kt & 3) * 2 + 0) * 512);
            gload_lds16(pA1 + kt * 32, Aw + ((kt & 3) * 2 + 1) * 512);
        }
        computeTile(s);
    }
    asm volatile("s_waitcnt vmcnt(2)" ::: "memory");
    __builtin_amdgcn_sched_barrier(0);
    computeTile(11);
    asm volatile("s_waitcnt vmcnt(0)" ::: "memory");
    __builtin_amdgcn_sched_barrier(0);
    computeTile(12);

    // ---- epilogue: LDS-bounced coalesced stores + fused stats ----
    u16* tile = lds;                     // 256x80 u16 = 40,960 B (lds now dead)
    __syncthreads();
    if (STATS) for (int i = t; i < 160; i += 512) sst[i] = 0.f;
    if (STATS) __syncthreads();

    float ssum[5], sqq[5];
#pragma unroll
    for (int c = 0; c < 5; ++c) { ssum[c] = 0.f; sqq[c] = 0.f; }
#pragma unroll
    for (int i = 0; i < 2; ++i) {
        const int lrow0 = w * 32 + i * 16 + (l >> 4) * 4;
#pragma unroll
        for (int c = 0; c < 5; ++c) {
            const int lcol = c * 16 + (l & 15);
            const float bv = bias[bn + lcol];
#pragma unroll
            for (int r = 0; r < 4; ++r) {
                const int lrow = lrow0 + r;
                float z = acc[i][c][r] + bv;
                tile[lrow * 80 + lcol] = f2bf(z);
                if (STATS && bm + lrow < M) { ssum[c] += z; sqq[c] += z * z; }
            }
        }
    }
    __syncthreads();
    // coalesced copy-out: 2560 16B chunks, 5 per thread
#pragma unroll
    for (int j = 0; j < 5; ++j) {
        int chunk = t + j * 512;
        int row = chunk / 10, c8 = chunk % 10;
        if (bm + row < M) {
            u16x8 v = *(const u16x8*)(tile + row * 80 + c8 * 8);
            *(u16x8*)(out + (long)(bm + row) * H + bn + c8 * 8) = v;
        }
    }
    if (STATS) {
        const int rep = wgid & (SREP - 1);
#pragma unroll
        for (int c = 0; c < 5; ++c) {
            ssum[c] += __shfl_xor(ssum[c], 16); ssum[c] += __shfl_xor(ssum[c], 32);
            sqq[c]  += __shfl_xor(sqq[c], 16);  sqq[c]  += __shfl_xor(sqq[c], 32);
        }
        if (l < 16) {
#pragma unroll
            for (int c = 0; c < 5; ++c) {
                atomicAdd(&sst[c * 16 + l], ssum[c]);
                atomicAdd(&sst[80 + c * 16 + l], sqq[c]);
            }
        }
        __syncthreads();
        if (t < 80)       atomicAdd(&statsOut[rep * 2 * KP + bn + t], sst[t]);
        else if (t < 160) atomicAdd(&statsOut[rep * 2 * KP + KP + bn + (t - 80)], sst[t]);
    }
}

// ---------------- pooled f2 ----------------

__global__ __launch_bounds__(256) void k_poolf(const u16* __restrict__ z,
                                               const float* __restrict__ statsIn,
                                               const float* __restrict__ gw,
                                               const float* __restrict__ be,
                                               const int* __restrict__ batch,
                                               float* __restrict__ pf) {
    __shared__ float sdS[400];
    __shared__ float sdH[400];
    int t = threadIdx.x;
    for (int j = t; j < 400; j += 256) {
        float s = 0.f, q = 0.f;
#pragma unroll
        for (int r = 0; r < SREP; ++r) {
            s += statsIn[r * 2 * KP + j];
            q += statsIn[r * 2 * KP + KP + j];
        }
        float m = s / NN, v = fmaxf(q / NN - m * m, 0.f);
        float rs = rsqrtf(v + EPS);
        float sc = gw[j] * rs;
        sdS[j] = sc;
        sdH[j] = be[j] - m * sc;
    }
    __syncthreads();
    if (t >= 250) return;
    const int sub = t / 50, seg = t % 50;
    float sc[8], sh[8];
#pragma unroll
    for (int q = 0; q < 8; ++q) {
        sc[q] = sdS[seg * 8 + q];
        sh[q] = sdH[seg * 8 + q];
    }
    int rows = (NN + gridDim.x - 1) / gridDim.x;
    int r0 = blockIdx.x * rows;
    int r1 = min(r0 + rows, NN);
    float acc[8] = {0.f, 0.f, 0.f, 0.f, 0.f, 0.f, 0.f, 0.f};
    int gp = -1;
    for (int r = r0 + sub; r < r1; r += 5) {
        int gg = batch[r];
        if (gg != gp) {
            if (gp >= 0) {
#pragma unroll
                for (int q = 0; q < 8; ++q)
                    atomicAdd(&pf[(long)gp * 400 + seg * 8 + q], acc[q]);
            }
#pragma unroll
            for (int q = 0; q < 8; ++q) acc[q] = 0.f;
            gp = gg;
        }
        u16x8 v = *(const u16x8*)(z + (long)r * H + seg * 8);
#pragma unroll
        for (int q = 0; q < 8; ++q)
            acc[q] += fmaxf(fmaf(bf2f(v[q]), sc[q], sh[q]), 0.f);
    }
    if (gp >= 0) {
#pragma unroll
        for (int q = 0; q < 8; ++q)
            atomicAdd(&pf[(long)gp * 400 + seg * 8 + q], acc[q]);
    }
}

// ---------------- poolgemm ----------------

__global__ __launch_bounds__(256) void k_poolgemm(const float* __restrict__ pf,
                                                  const float* __restrict__ w30,
                                                  const float* __restrict__ w312,
                                                  const float* __restrict__ b30,
                                                  const float* __restrict__ b312,
                                                  const int* __restrict__ cnt,
                                                  float* __restrict__ pools) {
    __shared__ __align__(16) float xr[400];
    int g = blockIdx.x, L = blockIdx.y, t = threadIdx.x;
    const float* w = (L == 0) ? w30 : w312 + (size_t)(L - 1) * 400 * 400;
    const float* b = (L == 0) ? b30 : b312 + (L - 1) * 400;
    for (int i = t; i < 400; i += 256) xr[i] = pf[((long)L * NG + g) * 400 + i];
    __syncthreads();
    float cg = (float)cnt[g];
    for (int c = t; c < 400; c += 256) {
        const float4* wr = (const float4*)(w + (long)c * 400);
        const float4* xv = (const float4*)xr;
        float s0 = 0.f, s1 = 0.f, s2 = 0.f, s3 = 0.f;
        for (int q = 0; q < 100; ++q) {
            float4 a = xv[q], bb = wr[q];
            s0 = fmaf(a.x, bb.x, s0); s1 = fmaf(a.y, bb.y, s1);
            s2 = fmaf(a.z, bb.z, s2); s3 = fmaf(a.w, bb.w, s3);
        }
        pools[(long)g * 1200 + L * 400 + c] = s0 + s1 + s2 + s3 + cg * b[c];
    }
}

// ---------------- readout ----------------

__global__ __launch_bounds__(256) void k_lin1(const float* __restrict__ pools,
                                              const float* __restrict__ w1,
                                              const float* __restrict__ b1,
                                              float* __restrict__ zz) {
    __shared__ __align__(16) float xg[8][1200];
    const int bandj = blockIdx.x * 40;
    const int g0 = blockIdx.y * 8;
    const int t = threadIdx.x;
    for (int i = t; i < 9600; i += 256)
        xg[i / 1200][i % 1200] = pools[(long)(g0 + i / 1200) * 1200 + (i % 1200)];
    __syncthreads();
    const int wv = t >> 6, l = t & 63;
    for (int jj = wv; jj < 40; jj += 4) {
        const int j = bandj + jj;
        const float4* wr = (const float4*)(w1 + (long)j * 1200);
        float s[8] = {0.f, 0.f, 0.f, 0.f, 0.f, 0.f, 0.f, 0.f};
        for (int q = l; q < 300; q += 64) {
            float4 wq = wr[q];
#pragma unroll
            for (int g = 0; g < 8; ++g) {
                float4 xv = *(const float4*)&xg[g][q * 4];
                s[g] = fmaf(wq.x, xv.x, s[g]);
                s[g] = fmaf(wq.y, xv.y, s[g]);
                s[g] = fmaf(wq.z, xv.z, s[g]);
                s[g] = fmaf(wq.w, xv.w, s[g]);
            }
        }
#pragma unroll
        for (int g = 0; g < 8; ++g)
#pragma unroll
            for (int o = 32; o; o >>= 1) s[g] += __shfl_xor(s[g], o);
        if (l == 0) {
            const float bj = b1[j];
#pragma unroll
            for (int g = 0; g < 8; ++g)
                zz[(long)(g0 + g) * 600 + j] = fmaxf(s[g] + bj, 0.f);
        }
    }
}

__global__ __launch_bounds__(64) void k_lin2(const float* __restrict__ zz,
                                             const float* __restrict__ w2,
                                             const float* __restrict__ b2,
                                             float* __restrict__ out) {
    int g = blockIdx.x;
    int l = threadIdx.x;
    float p[NC];
#pragma unroll
    for (int c = 0; c < NC; ++c) p[c] = 0.f;
    for (int k = l; k < 600; k += 64) {
        float zv = zz[(long)g * 600 + k];
#pragma unroll
        for (int c = 0; c < NC; ++c) p[c] = fmaf(zv, w2[c * 600 + k], p[c]);
    }
#pragma unroll
    for (int c = 0; c < NC; ++c)
#pragma unroll
        for (int o = 32; o; o >>= 1) p[c] += __shfl_xor(p[c], o);
    if (l == 0) {
        float lg[NC];
        float mx = -1e30f;
#pragma unroll
        for (int c = 0; c < NC; ++c) { lg[c] = p[c] + b2[c]; mx = fmaxf(mx, lg[c]); }
        float se = 0.f;
#pragma unroll
        for (int c = 0; c < NC; ++c) se += expf(lg[c] - mx);
        float lse = logf(se);
#pragma unroll
        for (int c = 0; c < NC; ++c) out[(long)g * NC + c] = lg[c] - mx - lse;
    }
}

// ---------------- launch ----------------

extern "C" void kernel_launch(void* const* d_in, const int* in_sizes, int n_in,
                              void* d_out, int out_size, void* d_ws, size_t ws_size,
                              hipStream_t stream) {
    const float* x      = (const float*)d_in[0];
    const int*   ei     = (const int*)d_in[1];
    const int*   batch  = (const int*)d_in[2];
    const float* c0_w1  = (const float*)d_in[4];
    const float* c0_b1  = (const float*)d_in[5];
    const float* c0_g1  = (const float*)d_in[6];
    const float* c0_be1 = (const float*)d_in[7];
    const float* c0_w2  = (const float*)d_in[8];
    const float* c0_b2  = (const float*)d_in[9];
    const float* c0_g2  = (const float*)d_in[10];
    const float* c0_be2 = (const float*)d_in[11];
    const float* c0_w3  = (const float*)d_in[12];
    const float* c0_b3  = (const float*)d_in[13];
    const float* cw1    = (const float*)d_in[14];
    const float* cb1    = (const float*)d_in[15];
    const float* cg1    = (const float*)d_in[16];
    const float* cbe1   = (const float*)d_in[17];
    const float* cw2    = (const float*)d_in[18];
    const float* cb2    = (const float*)d_in[19];
    const float* cg2    = (const float*)d_in[20];
    const float* cbe2   = (const float*)d_in[21];
    const float* cw3    = (const float*)d_in[22];
    const float* cb3    = (const float*)d_in[23];
    const float* lin1_w = (const float*)d_in[24];
    const float* lin1_b = (const float*)d_in[25];
    const float* lin2_w = (const float*)d_in[26];
    const float* lin2_b = (const float*)d_in[27];

    const int* src = ei;
    const int* dst = ei + NE;

    char* ws = (char*)d_ws;
    size_t off = 0;
    auto alloc = [&](size_t bytes) {
        void* p = ws + off;
        off += (bytes + 255) & ~(size_t)255;
        return p;
    };
    u16*   bufh   = (u16*)alloc((size_t)NN * H * 2 + 128);   // K-tail overread pad
    u16*   bufa   = (u16*)alloc((size_t)NN * H * 2 + 128);
    float* agg0   = (float*)alloc((size_t)NN * 4 * 4);
    // ---- contiguous zero region: deg | statsA | mom | pf | cnt ----
    char*  zstart = ws + off;
    int*   deg    = (int*)alloc((size_t)NN * 4);
    float* statsA = (float*)alloc((size_t)6 * SSLOT * 4);
    float* mom    = (float*)alloc(14 * 4);
    float* pf     = (float*)alloc((size_t)3 * NG * 400 * 4);
    int*   cnt    = (int*)alloc((size_t)NG * 4);
    size_t zbytes = (size_t)((ws + off) - zstart);
    // ---- rest ----
    float* pools  = (float*)alloc((size_t)NG * 3 * H * 4);
    float* zz     = (float*)alloc((size_t)NG * 600 * 4);
    float* bb1    = (float*)alloc(400 * 4);
    float* bb2    = (float*)alloc(400 * 4);
    u16*   wpad   = (u16*)alloc((size_t)5 * 400 * KP * 2);
    int*   rowp   = (int*)alloc((size_t)(NN + 1) * 4);
    int*   cur    = (int*)alloc((size_t)NN * 4);
    int*   csrc   = (int*)alloc((size_t)NE * 4);
    int*   part   = (int*)alloc((size_t)NN * 4);
    int*   btot   = (int*)alloc((size_t)NB1 * 4);

    auto wp   = [&](int mat) { return wpad + (size_t)mat * 400 * KP; };
    auto slot = [&](int i)   { return statsA + (size_t)i * SSLOT; };

    hipMemsetAsync(zstart, 0, zbytes, stream);

    k_wprep<<<346, 256, 0, stream>>>(c0_w2, cw2, cw1, c0_w3, cw3, c0_b3, cb3,
                                     wpad, bb1, bb2);

    // CSR build + graph counts
    k_count<<<(NE + 255) / 256, 256, 0, stream>>>(dst, deg);
    k_scan1<<<NB1, 256, 0, stream>>>(deg, part, btot);
    k_scan2<<<1, 256, 0, stream>>>(btot);
    k_scan3<<<NB1, 256, 0, stream>>>(part, btot, deg, rowp, cur, batch, cnt);
    k_scatter<<<(NE + 255) / 256, 256, 0, stream>>>(src, dst, cur, csrc);

    const int ngemm = ((NN + 255) / 256) * 5;   // 980 blocks (256-row panels)

    // layer 0
    k_agg0<<<NB1, 256, 0, stream>>>(x, rowp, csrc, agg0, mom);
    k_lin0<<<NLIN0 + 2, 256, 0, stream>>>(agg0, c0_w1, c0_b1, bufh, mom, slot(0));
    gemm_mfma<true><<<ngemm, 512, 0, stream>>>(bufh, wp(0), c0_b2, c0_g1, c0_be1,
                                               slot(0), slot(1), bufa, NN);         // z2
    gemm_mfma<false><<<ngemm, 512, 0, stream>>>(bufa, wp(3), bb1, c0_g2, c0_be2,
                                                slot(1), nullptr, bufh, NN);        // y2
    k_poolf<<<512, 256, 0, stream>>>(bufa, slot(1), c0_g2, c0_be2, batch, pf);

    // layer 1
    k_aggH<<<(NN + 3) / 4, 256, 0, stream>>>(bufh, rowp, csrc, cb1, bufa);          // z1'
    k_statsv<<<256, 256, 0, stream>>>(bufa, slot(2));
    gemm_mfma<true><<<ngemm, 512, 0, stream>>>(bufa, wp(1), cb2, cg1, cbe1,
                                               slot(2), slot(3), bufh, NN);         // z2'
    gemm_mfma<false><<<ngemm, 512, 0, stream>>>(bufh, wp(4), bb2, cg2, cbe2,
                                                slot(3), nullptr, bufa, NN);        // y2'
    k_poolf<<<512, 256, 0, stream>>>(bufh, slot(3), cg2, cbe2, batch, pf + (size_t)NG * 400);

    // layer 2
    k_aggH<<<(NN + 3) / 4, 256, 0, stream>>>(bufa, rowp, csrc, cb1 + 400, bufh);    // z1''
    k_statsv<<<256, 256, 0, stream>>>(bufh, slot(4));
    gemm_mfma<true><<<ngemm, 512, 0, stream>>>(bufh, wp(2), cb2 + 400, cg1 + 400,
                                               cbe1 + 400, slot(4), slot(5), bufa, NN); // z2''
    k_poolf<<<512, 256, 0, stream>>>(bufa, slot(5), cg2 + 400, cbe2 + 400, batch,
                                     pf + (size_t)2 * NG * 400);

    // pools = pf * W3^T + cnt*b3, then readout
    dim3 gp(NG, 3);
    k_poolgemm<<<gp, 256, 0, stream>>>(pf, c0_w3, cw3, c0_b3, cb3, cnt, pools);
    dim3 gl1(15, 16);
    k_lin1<<<gl1, 256, 0, stream>>>(pools, lin1_w, lin1_b, zz);
    k_lin2<<<NG, 64, 0, stream>>>(zz, lin2_w, lin2_b, (float*)d_out);
}

// Round 19
// 751.695 us; speedup vs baseline: 1.0579x; 1.0579x over previous
//
#include <hip/hip_runtime.h>
#include <hip/hip_bf16.h>
#include <math.h>
#include <cstdint>

static constexpr int NN = 50000;   // nodes
static constexpr int NE = 400000;  // edges
static constexpr int H  = 400;     // hidden dim
static constexpr int NG = 128;     // graphs
static constexpr int NC = 10;      // classes
static constexpr float EPS = 1e-5f;
static constexpr int NB1 = (NN + 255) / 256;   // 196 scan blocks
static constexpr int KP  = 416;                // padded K for weights
static constexpr int SREP = 8;                 // stats replicas (contention spread)
static constexpr int SSLOT = SREP * 2 * KP;    // floats per stats slot

typedef unsigned short u16;
typedef __attribute__((ext_vector_type(8))) unsigned short u16x8;
typedef __attribute__((ext_vector_type(4))) unsigned short u16x4;
typedef __attribute__((ext_vector_type(8))) short bf16x8;
typedef __attribute__((ext_vector_type(4))) float f32x4;

__device__ __forceinline__ float bf2f(u16 u) {
    return __uint_as_float(((uint32_t)u) << 16);
}
__device__ __forceinline__ u16 f2bf(float f) {
    uint32_t u = __float_as_uint(f);
    return (u16)((u + 0x7FFFu + ((u >> 16) & 1u)) >> 16);
}
__device__ __forceinline__ void gload_lds16(const void* g, void* lds) {
    __builtin_amdgcn_global_load_lds((const __attribute__((address_space(1))) void*)g,
                                     (__attribute__((address_space(3))) void*)lds, 16, 0, 0);
}

// BN+ReLU on a bf16x8 fragment using HW packed bf16 convert
__device__ __forceinline__ bf16x8 bnrelu8(bf16x8 a, const float* __restrict__ scp,
                                          const float* __restrict__ shp) {
    union { bf16x8 v; uint32_t u[4]; } in, out;
    in.v = a;
#pragma unroll
    for (int p = 0; p < 4; ++p) {
        float lo = __uint_as_float(in.u[p] << 16);
        float hi = __uint_as_float(in.u[p] & 0xFFFF0000u);
        lo = fmaxf(fmaf(lo, scp[2 * p], shp[2 * p]), 0.f);
        hi = fmaxf(fmaf(hi, scp[2 * p + 1], shp[2 * p + 1]), 0.f);
        asm("v_cvt_pk_bf16_f32 %0, %1, %2" : "=v"(out.u[p]) : "v"(lo), "v"(hi));
    }
    return out.v;
}

// ---------------- CSR build ----------------

__global__ void k_count(const int* __restrict__ dst, int* __restrict__ deg) {
    int e = blockIdx.x * blockDim.x + threadIdx.x;
    if (e < NE) atomicAdd(&deg[dst[e]], 1);
}

__global__ __launch_bounds__(256) void k_scan1(const int* __restrict__ deg,
                                               int* __restrict__ part,
                                               int* __restrict__ btot) {
    __shared__ int sd[256];
    int t = threadIdx.x;
    int i = blockIdx.x * 256 + t;
    int v = (i < NN) ? deg[i] : 0;
    sd[t] = v;
    __syncthreads();
#pragma unroll
    for (int off = 1; off < 256; off <<= 1) {
        int x = (t >= off) ? sd[t - off] : 0;
        __syncthreads();
        sd[t] += x;
        __syncthreads();
    }
    if (i < NN) part[i] = sd[t];
    if (t == 255) btot[blockIdx.x] = sd[255];
}

__global__ __launch_bounds__(256) void k_scan2(int* __restrict__ btot) {
    __shared__ int sd[256];
    int t = threadIdx.x;
    int v = (t < NB1) ? btot[t] : 0;
    sd[t] = v;
    __syncthreads();
#pragma unroll
    for (int off = 1; off < 256; off <<= 1) {
        int x = (t >= off) ? sd[t - off] : 0;
        __syncthreads();
        sd[t] += x;
        __syncthreads();
    }
    if (t < NB1) btot[t] = sd[t];
}

// scan3 + graph-count fused
__global__ __launch_bounds__(256) void k_scan3(const int* __restrict__ part,
                                               const int* __restrict__ btot,
                                               const int* __restrict__ deg,
                                               int* __restrict__ rowp,
                                               int* __restrict__ cur,
                                               const int* __restrict__ batch,
                                               int* __restrict__ cnt) {
    __shared__ int hh[NG];
    int t = threadIdx.x;
    int i = blockIdx.x * 256 + t;
    if (i < NN) {
        int s = part[i] + (blockIdx.x ? btot[blockIdx.x - 1] : 0);
        rowp[i + 1] = s;
        cur[i] = s - deg[i];
    }
    if (i == 0) rowp[0] = 0;
    for (int j = t; j < NG; j += 256) hh[j] = 0;
    __syncthreads();
    if (i < NN) atomicAdd(&hh[batch[i]], 1);
    __syncthreads();
    for (int j = t; j < NG; j += 256)
        if (hh[j]) atomicAdd(&cnt[j], hh[j]);
}

__global__ void k_scatter(const int* __restrict__ src, const int* __restrict__ dst,
                          int* __restrict__ cur, int* __restrict__ csrc) {
    int e = blockIdx.x * blockDim.x + threadIdx.x;
    if (e < NE) {
        int d = dst[e];
        int p = atomicAdd(&cur[d], 1);
        csrc[p] = src[e];
    }
}

// ---------------- unified weight prep: cvt x3 | merge x2 | bias x2 (flat grid) ----------------

__global__ __launch_bounds__(256) void k_wprep(const float* __restrict__ c0_w2,
                                               const float* __restrict__ cw2,
                                               const float* __restrict__ cw1,
                                               const float* __restrict__ c0_w3,
                                               const float* __restrict__ cw3,
                                               const float* __restrict__ c0_b3,
                                               const float* __restrict__ cb3,
                                               u16* __restrict__ wpad,
                                               float* __restrict__ bb1,
                                               float* __restrict__ bb2) {
    const int b = blockIdx.x;
    const int t = threadIdx.x;
    if (b < 244) {
        int i = b * 256 + t;   // over 3*400*52
        if (i >= 3 * 400 * 52) return;
        int rc = i / 52;
        int c8 = (i % 52) * 8;
        u16x8 o = {0, 0, 0, 0, 0, 0, 0, 0};
        if (c8 < 400) {
            int mat = rc / 400, row = rc % 400;
            const float* s = (mat == 0 ? c0_w2 : mat == 1 ? cw2 : cw2 + 160000)
                             + (long)row * 400;
            float4 a = *(const float4*)(s + c8);
            float4 bb = *(const float4*)(s + c8 + 4);
            o[0] = f2bf(a.x); o[1] = f2bf(a.y); o[2] = f2bf(a.z); o[3] = f2bf(a.w);
            o[4] = f2bf(bb.x); o[5] = f2bf(bb.y); o[6] = f2bf(bb.z); o[7] = f2bf(bb.w);
        }
        *(u16x8*)(wpad + (long)rc * KP + c8) = o;
    } else if (b < 342) {
        __shared__ float As[16][68];
        __shared__ float Bs[16][68];
        const int b2 = (b < 293) ? b - 244 : b - 293;
        const float* Wa = (b < 293) ? cw1 : cw1 + 160000;
        const float* Wb = (b < 293) ? c0_w3 : cw3;
        u16* dst = wpad + (size_t)((b < 293) ? 3 : 4) * 400 * KP;
        const int bc = (b2 / 7) * 64, bj = (b2 % 7) * 64;
        const int tx = t & 15, ty = t >> 4;
        float acc[4][4] = {};
        for (int k0 = 0; k0 < 400; k0 += 16) {
            {
                int c = bc + (t >> 2);
                int kq = (t & 3) * 4;
                float4 v = make_float4(0.f, 0.f, 0.f, 0.f);
                if (c < 400) v = *(const float4*)(Wa + (long)c * 400 + k0 + kq);
                As[kq + 0][t >> 2] = v.x; As[kq + 1][t >> 2] = v.y;
                As[kq + 2][t >> 2] = v.z; As[kq + 3][t >> 2] = v.w;
            }
            {
                int k = k0 + (t >> 4);
                int jq = (t & 15) * 4;
                int j = bj + jq;
                float4 v = make_float4(0.f, 0.f, 0.f, 0.f);
                if (j < 400) v = *(const float4*)(Wb + (long)k * 400 + j);
                Bs[t >> 4][jq + 0] = v.x; Bs[t >> 4][jq + 1] = v.y;
                Bs[t >> 4][jq + 2] = v.z; Bs[t >> 4][jq + 3] = v.w;
            }
            __syncthreads();
#pragma unroll
            for (int kk = 0; kk < 16; ++kk) {
                float4 av = *(const float4*)&As[kk][ty * 4];
                float4 bv = *(const float4*)&Bs[kk][tx * 4];
                float a[4] = {av.x, av.y, av.z, av.w};
                float bb[4] = {bv.x, bv.y, bv.z, bv.w};
#pragma unroll
                for (int i = 0; i < 4; ++i)
#pragma unroll
                    for (int j = 0; j < 4; ++j)
                        acc[i][j] = fmaf(a[i], bb[j], acc[i][j]);
            }
            __syncthreads();
        }
#pragma unroll
        for (int i = 0; i < 4; ++i) {
            int c = bc + ty * 4 + i;
            if (c >= 400) continue;
#pragma unroll
            for (int j = 0; j < 4; ++j) {
                int col = bj + tx * 4 + j;
                if (col < KP) dst[(long)c * KP + col] = (col < 400) ? f2bf(acc[i][j]) : 0;
            }
        }
    } else {
        const int c = (b & 1) * 256 + t;
        if (c >= 400) return;
        const float* Wa = (b < 344) ? cw1 : cw1 + 160000;
        const float* bv = (b < 344) ? c0_b3 : cb3;
        float* out = (b < 344) ? bb1 : bb2;
        const float4* wr = (const float4*)(Wa + (long)c * 400);
        const float4* br = (const float4*)bv;
        float s0 = 0.f, s1 = 0.f, s2 = 0.f, s3 = 0.f;
        for (int q = 0; q < 100; ++q) {
            float4 a = wr[q], v = br[q];
            s0 = fmaf(a.x, v.x, s0); s1 = fmaf(a.y, v.y, s1);
            s2 = fmaf(a.z, v.z, s2); s3 = fmaf(a.w, v.w, s3);
        }
        out[c] = s0 + s1 + s2 + s3;
    }
}

// ---------------- agg0 + moments ----------------

__global__ __launch_bounds__(256) void k_agg0(const float* __restrict__ x,
                                              const int* __restrict__ rowp,
                                              const int* __restrict__ csrc,
                                              float* __restrict__ out,
                                              float* __restrict__ mom) {
    __shared__ float ws[4][14];
    int n = blockIdx.x * blockDim.x + threadIdx.x;
    float4 acc = make_float4(0.f, 0.f, 0.f, 0.f);
    if (n < NN) {
        int b = rowp[n], e = rowp[n + 1];
        for (int p = b; p < e; ++p) {
            float4 v = ((const float4*)x)[csrc[p]];
            acc.x += v.x; acc.y += v.y; acc.z += v.z; acc.w += v.w;
        }
        ((float4*)out)[n] = acc;
    }
    float mv[14] = {acc.x, acc.y, acc.z, acc.w,
                    acc.x * acc.x, acc.x * acc.y, acc.x * acc.z, acc.x * acc.w,
                    acc.y * acc.y, acc.y * acc.z, acc.y * acc.w,
                    acc.z * acc.z, acc.z * acc.w, acc.w * acc.w};
    int wv = threadIdx.x >> 6, l = threadIdx.x & 63;
#pragma unroll
    for (int i = 0; i < 14; ++i) {
        float s = mv[i];
#pragma unroll
        for (int o = 32; o; o >>= 1) s += __shfl_xor(s, o);
        if (l == 0) ws[wv][i] = s;
    }
    __syncthreads();
    if (threadIdx.x < 14) {
        float s = ws[0][threadIdx.x] + ws[1][threadIdx.x] + ws[2][threadIdx.x] + ws[3][threadIdx.x];
        atomicAdd(&mom[threadIdx.x], s);
    }
}

// ---------------- aggH: one wave per node (latency-optimal) ----------------

__global__ __launch_bounds__(256) void k_aggH(const u16* __restrict__ h,
                                              const int* __restrict__ rowp,
                                              const int* __restrict__ csrc,
                                              const float* __restrict__ bias,
                                              u16* __restrict__ out) {
    int n = (blockIdx.x << 2) + (threadIdx.x >> 6);
    if (n >= NN) return;
    int l = threadIdx.x & 63;
    if (l >= 50) return;
    float4 b0 = *(const float4*)(bias + l * 8);
    float4 b1 = *(const float4*)(bias + l * 8 + 4);
    float acc[8] = {b0.x, b0.y, b0.z, b0.w, b1.x, b1.y, b1.z, b1.w};
    int b = rowp[n], e = rowp[n + 1];
    for (int p = b; p < e; ++p) {
        const u16* r = h + (long)csrc[p] * H + l * 8;
        u16x8 v = *(const u16x8*)r;
#pragma unroll
        for (int q = 0; q < 8; ++q) acc[q] += bf2f(v[q]);
    }
    u16x8 o;
#pragma unroll
    for (int q = 0; q < 8; ++q) o[q] = f2bf(acc[q]);
    *(u16x8*)(out + (long)n * H + l * 8) = o;
}

// ---------------- first linear (K = 4) + fused analytic z1 stats ----------------

static constexpr int NLIN0 = (int)(((long)NN * 100 + 255) / 256);

__global__ void k_lin0(const float* __restrict__ a4, const float* __restrict__ w,
                       const float* __restrict__ b, u16* __restrict__ out,
                       const float* __restrict__ mom, float* __restrict__ slot0) {
    if (blockIdx.x >= NLIN0) {
        int j = (blockIdx.x - NLIN0) * 256 + threadIdx.x;
        if (j >= 400) return;
        float4 wv = ((const float4*)w)[j];
        float dot = wv.x * mom[0] + wv.y * mom[1] + wv.z * mom[2] + wv.w * mom[3];
        float quad = wv.x * wv.x * mom[4] + 2.f * wv.x * wv.y * mom[5]
                   + 2.f * wv.x * wv.z * mom[6] + 2.f * wv.x * wv.w * mom[7]
                   + wv.y * wv.y * mom[8] + 2.f * wv.y * wv.z * mom[9]
                   + 2.f * wv.y * wv.w * mom[10] + wv.z * wv.z * mom[11]
                   + 2.f * wv.z * wv.w * mom[12] + wv.w * wv.w * mom[13];
        float bj = b[j];
        slot0[j] = dot + (float)NN * bj;
        slot0[KP + j] = quad + 2.f * bj * dot + (float)NN * bj * bj;
        return;
    }
    long i = (long)blockIdx.x * blockDim.x + threadIdx.x;
    if (i >= (long)NN * 100) return;
    int n = (int)(i / 100), q = (int)(i - (long)n * 100);
    int j0 = q * 4;
    float4 av = ((const float4*)a4)[n];
    u16x4 o;
#pragma unroll
    for (int jj = 0; jj < 4; ++jj) {
        float4 wv = ((const float4*)w)[j0 + jj];
        float s = fmaf(av.x, wv.x, fmaf(av.y, wv.y, fmaf(av.z, wv.z, av.w * wv.w)));
        o[jj] = f2bf(s + b[j0 + jj]);
    }
    *(u16x4*)(out + (long)n * H + j0) = o;
}

// ---------------- BN stats over bf16 buffer -> replica slot ----------------

__global__ __launch_bounds__(256) void k_statsv(const u16* __restrict__ z,
                                                float* __restrict__ stats) {
    __shared__ float ls[800];
    int t = threadIdx.x;
    for (int i = t; i < 800; i += 256) ls[i] = 0.f;
    __syncthreads();
    if (t < 250) {
        int sub = t / 50, seg = t % 50;
        float s[8] = {0, 0, 0, 0, 0, 0, 0, 0};
        float q[8] = {0, 0, 0, 0, 0, 0, 0, 0};
        for (int r = blockIdx.x * 5 + sub; r < NN; r += gridDim.x * 5) {
            u16x8 v = *(const u16x8*)(z + (long)r * H + seg * 8);
#pragma unroll
            for (int j = 0; j < 8; ++j) {
                float f = bf2f(v[j]);
                s[j] += f; q[j] += f * f;
            }
        }
#pragma unroll
        for (int j = 0; j < 8; ++j) {
            atomicAdd(&ls[seg * 8 + j], s[j]);
            atomicAdd(&ls[400 + seg * 8 + j], q[j]);
        }
    }
    __syncthreads();
    const int rep = blockIdx.x & (SREP - 1);
    for (int i = t; i < 800; i += 256) {
        int col = (i < 400) ? i : (i - 400 + KP);
        atomicAdd(&stats[rep * 2 * KP + col], ls[i]);
    }
}

// ---------------- MFMA GEMM (R17 structure): fused BN-finalize + BN/ReLU + stats ----------------

template <bool STATS>
__global__ __launch_bounds__(256) void gemm_mfma(const u16* __restrict__ A,
                                                 const u16* __restrict__ Wp,
                                                 const float* __restrict__ bias,
                                                 const float* __restrict__ bnG,
                                                 const float* __restrict__ bnBe,
                                                 const float* __restrict__ statsIn,
                                                 float* __restrict__ statsOut,
                                                 u16* __restrict__ out, int M) {
    constexpr int BUF = 6656;            // u16 per buffer: A 4096 + B 2560
    __shared__ u16 lds[3 * BUF];         // 39,936 B
    __shared__ float sdScale[KP];
    __shared__ float sdShift[KP];
    __shared__ float sst[160];

    const int t = threadIdx.x;
    // bijective XCD swizzle (nwg = 1955, not divisible by 8)
    const int nwg = gridDim.x;
    const int q8 = nwg >> 3, r8 = nwg & 7;
    const int xcd = blockIdx.x & 7, jj = blockIdx.x >> 3;
    const int wgid = (xcd < r8 ? xcd * (q8 + 1) : r8 * (q8 + 1) + (xcd - r8) * q8) + jj;
    const int bm = (wgid / 5) * 128;
    const int bn = (wgid % 5) * 80;
    const int w = t >> 6, l = t & 63;

    // ---- BN finalize prologue ----
    for (int j = t; j < KP; j += 256) {
        float s = 0.f, q = 0.f;
#pragma unroll
        for (int r = 0; r < SREP; ++r) {
            s += statsIn[r * 2 * KP + j];
            q += statsIn[r * 2 * KP + KP + j];
        }
        float sc = 0.f, sh = 0.f;
        if (j < H) {
            float m = s / NN;
            float v = fmaxf(q / NN - m * m, 0.f);
            float rs = rsqrtf(v + EPS);
            sc = bnG[j] * rs;
            sh = bnBe[j] - m * sc;
        }
        sdScale[j] = sc;
        sdShift[j] = sh;
    }

    const int srow = l >> 2;
    const int sck  = ((l & 3) ^ ((l >> 3) & 3)) * 8;   // source-side XOR swizzle

    auto stageTile = [&](int b, int kt) {
        u16* dst = lds + b * BUF;
        const int k0 = kt * 32;
        long g0 = (long)bm + w * 16 + srow;
        long g1 = g0 + 64;
        if (g0 > M - 1) g0 = M - 1;
        if (g1 > M - 1) g1 = M - 1;
        gload_lds16(A + g0 * 400 + k0 + sck, dst + w * 512);
        gload_lds16(A + g1 * 400 + k0 + sck, dst + (w + 4) * 512);
        gload_lds16(Wp + (long)(bn + w * 16 + srow) * KP + k0 + sck,
                    dst + 4096 + w * 512);
        gload_lds16(Wp + (long)(bn + 64 + srow) * KP + k0 + sck,
                    dst + 4096 + 4 * 512);       // B seg 4 (x4 dup -> uniform 4 loads/wave)
    };

    f32x4 acc[2][5];
#pragma unroll
    for (int i = 0; i < 2; ++i)
#pragma unroll
        for (int c = 0; c < 5; ++c)
            acc[i][c] = (f32x4){0.f, 0.f, 0.f, 0.f};

    const int r16 = l & 15;
    const int cc  = l >> 4;
    const int swz = r16 * 32 + (((cc ^ ((r16 >> 1) & 3))) << 3);

    auto computeTile = [&](int b, int s) {
        const u16* base = lds + b * BUF;
        const u16* ab = base + w * 1024 + swz;
        const u16* bb = base + 4096 + swz;
        bf16x8 fa0 = *(const bf16x8*)ab;
        bf16x8 fa1 = *(const bf16x8*)(ab + 512);
        const int k = s * 32 + cc * 8;
        fa0 = bnrelu8(fa0, sdScale + k, sdShift + k);
        fa1 = bnrelu8(fa1, sdScale + k, sdShift + k);
        __builtin_amdgcn_s_setprio(1);
#pragma unroll
        for (int c = 0; c < 5; ++c) {
            bf16x8 fb = *(const bf16x8*)(bb + c * 512);
            acc[0][c] = __builtin_amdgcn_mfma_f32_16x16x32_bf16(fa0, fb, acc[0][c], 0, 0, 0);
            acc[1][c] = __builtin_amdgcn_mfma_f32_16x16x32_bf16(fa1, fb, acc[1][c], 0, 0, 0);
        }
        __builtin_amdgcn_s_setprio(0);
    };

    // prologue: tiles 0,1 in flight (8 loads/wave)
    stageTile(0, 0);
    stageTile(1, 1);

#pragma unroll 1
    for (int s = 0; s < 12; ++s) {
        asm volatile("s_waitcnt vmcnt(4)" ::: "memory");
        __builtin_amdgcn_s_barrier();
        if (s + 2 < 13) stageTile((s + 2) % 3, s + 2);
        computeTile(s % 3, s);
    }
    asm volatile("s_waitcnt vmcnt(0)" ::: "memory");
    __builtin_amdgcn_s_barrier();
    computeTile(12 % 3, 12);

    // ---- epilogue: LDS-bounced coalesced stores + fused stats ----
    u16* tile = lds;
    __syncthreads();
    if (STATS) for (int i = t; i < 160; i += 256) sst[i] = 0.f;
    if (STATS) __syncthreads();

    float ssum[5], sqq[5];
#pragma unroll
    for (int c = 0; c < 5; ++c) { ssum[c] = 0.f; sqq[c] = 0.f; }
#pragma unroll
    for (int i = 0; i < 2; ++i) {
        const int lrow0 = w * 32 + i * 16 + (l >> 4) * 4;
#pragma unroll
        for (int c = 0; c < 5; ++c) {
            const int lcol = c * 16 + (l & 15);
            const float bv = bias[bn + lcol];
#pragma unroll
            for (int r = 0; r < 4; ++r) {
                const int lrow = lrow0 + r;
                float z = acc[i][c][r] + bv;
                tile[lrow * 80 + lcol] = f2bf(z);
                if (STATS && bm + lrow < M) { ssum[c] += z; sqq[c] += z * z; }
            }
        }
    }
    __syncthreads();
#pragma unroll
    for (int j = 0; j < 5; ++j) {
        int chunk = t + j * 256;
        int row = chunk / 10, c8 = chunk % 10;
        if (bm + row < M) {
            u16x8 v = *(const u16x8*)(tile + row * 80 + c8 * 8);
            *(u16x8*)(out + (long)(bm + row) * H + bn + c8 * 8) = v;
        }
    }
    if (STATS) {
        const int rep = wgid & (SREP - 1);
#pragma unroll
        for (int c = 0; c < 5; ++c) {
            ssum[c] += __shfl_xor(ssum[c], 16); ssum[c] += __shfl_xor(ssum[c], 32);
            sqq[c]  += __shfl_xor(sqq[c], 16);  sqq[c]  += __shfl_xor(sqq[c], 32);
        }
        if (l < 16) {
#pragma unroll
            for (int c = 0; c < 5; ++c) {
                atomicAdd(&sst[c * 16 + l], ssum[c]);
                atomicAdd(&sst[80 + c * 16 + l], sqq[c]);
            }
        }
        __syncthreads();
        if (t < 80)       atomicAdd(&statsOut[rep * 2 * KP + bn + t], sst[t]);
        else if (t < 160) atomicAdd(&statsOut[rep * 2 * KP + KP + bn + (t - 80)], sst[t]);
    }
}

// ---------------- pooled f2: pf[g][c] = sum_{n in g} relu(bn(z[n][c])) ----------------

__global__ __launch_bounds__(256) void k_poolf(const u16* __restrict__ z,
                                               const float* __restrict__ statsIn,
                                               const float* __restrict__ gw,
                                               const float* __restrict__ be,
                                               const int* __restrict__ batch,
                                               float* __restrict__ pf) {
    __shared__ float sdS[400];
    __shared__ float sdH[400];
    int t = threadIdx.x;
    for (int j = t; j < 400; j += 256) {
        float s = 0.f, q = 0.f;
#pragma unroll
        for (int r = 0; r < SREP; ++r) {
            s += statsIn[r * 2 * KP + j];
            q += statsIn[r * 2 * KP + KP + j];
        }
        float m = s / NN, v = fmaxf(q / NN - m * m, 0.f);
        float rs = rsqrtf(v + EPS);
        float sc = gw[j] * rs;
        sdS[j] = sc;
        sdH[j] = be[j] - m * sc;
    }
    __syncthreads();
    if (t >= 250) return;
    const int sub = t / 50, seg = t % 50;
    float sc[8], sh[8];
#pragma unroll
    for (int q = 0; q < 8; ++q) {
        sc[q] = sdS[seg * 8 + q];
        sh[q] = sdH[seg * 8 + q];
    }
    int rows = (NN + gridDim.x - 1) / gridDim.x;
    int r0 = blockIdx.x * rows;
    int r1 = min(r0 + rows, NN);
    float acc[8] = {0.f, 0.f, 0.f, 0.f, 0.f, 0.f, 0.f, 0.f};
    int gp = -1;
    for (int r = r0 + sub; r < r1; r += 5) {
        int gg = batch[r];
        if (gg != gp) {
            if (gp >= 0) {
#pragma unroll
                for (int q = 0; q < 8; ++q)
                    atomicAdd(&pf[(long)gp * 400 + seg * 8 + q], acc[q]);
            }
#pragma unroll
            for (int q = 0; q < 8; ++q) acc[q] = 0.f;
            gp = gg;
        }
        u16x8 v = *(const u16x8*)(z + (long)r * H + seg * 8);
#pragma unroll
        for (int q = 0; q < 8; ++q)
            acc[q] += fmaxf(fmaf(bf2f(v[q]), sc[q], sh[q]), 0.f);
    }
    if (gp >= 0) {
#pragma unroll
        for (int q = 0; q < 8; ++q)
            atomicAdd(&pf[(long)gp * 400 + seg * 8 + q], acc[q]);
    }
}

// ---------------- pools[g][L*400+c] = pf[L][g]·W3_L[c]ᵀ + cnt[g]*b3_L[c] ----------------

__global__ __launch_bounds__(256) void k_poolgemm(const float* __restrict__ pf,
                                                  const float* __restrict__ w30,
                                                  const float* __restrict__ w312,
                                                  const float* __restrict__ b30,
                                                  const float* __restrict__ b312,
                                                  const int* __restrict__ cnt,
                                                  float* __restrict__ pools) {
    __shared__ __align__(16) float xr[400];
    int g = blockIdx.x, L = blockIdx.y, t = threadIdx.x;
    const float* w = (L == 0) ? w30 : w312 + (size_t)(L - 1) * 400 * 400;
    const float* b = (L == 0) ? b30 : b312 + (L - 1) * 400;
    for (int i = t; i < 400; i += 256) xr[i] = pf[((long)L * NG + g) * 400 + i];
    __syncthreads();
    float cg = (float)cnt[g];
    for (int c = t; c < 400; c += 256) {
        const float4* wr = (const float4*)(w + (long)c * 400);
        const float4* xv = (const float4*)xr;
        float s0 = 0.f, s1 = 0.f, s2 = 0.f, s3 = 0.f;
        for (int q = 0; q < 100; ++q) {
            float4 a = xv[q], bb = wr[q];
            s0 = fmaf(a.x, bb.x, s0); s1 = fmaf(a.y, bb.y, s1);
            s2 = fmaf(a.z, bb.z, s2); s3 = fmaf(a.w, bb.w, s3);
        }
        pools[(long)g * 1200 + L * 400 + c] = s0 + s1 + s2 + s3 + cg * b[c];
    }
}

// ---------------- readout ----------------

__global__ __launch_bounds__(256) void k_lin1(const float* __restrict__ pools,
                                              const float* __restrict__ w1,
                                              const float* __restrict__ b1,
                                              float* __restrict__ zz) {
    __shared__ __align__(16) float xg[8][1200];
    const int bandj = blockIdx.x * 40;
    const int g0 = blockIdx.y * 8;
    const int t = threadIdx.x;
    for (int i = t; i < 9600; i += 256)
        xg[i / 1200][i % 1200] = pools[(long)(g0 + i / 1200) * 1200 + (i % 1200)];
    __syncthreads();
    const int wv = t >> 6, l = t & 63;
    for (int jj = wv; jj < 40; jj += 4) {
        const int j = bandj + jj;
        const float4* wr = (const float4*)(w1 + (long)j * 1200);
        float s[8] = {0.f, 0.f, 0.f, 0.f, 0.f, 0.f, 0.f, 0.f};
        for (int q = l; q < 300; q += 64) {
            float4 wq = wr[q];
#pragma unroll
            for (int g = 0; g < 8; ++g) {
                float4 xv = *(const float4*)&xg[g][q * 4];
                s[g] = fmaf(wq.x, xv.x, s[g]);
                s[g] = fmaf(wq.y, xv.y, s[g]);
                s[g] = fmaf(wq.z, xv.z, s[g]);
                s[g] = fmaf(wq.w, xv.w, s[g]);
            }
        }
#pragma unroll
        for (int g = 0; g < 8; ++g)
#pragma unroll
            for (int o = 32; o; o >>= 1) s[g] += __shfl_xor(s[g], o);
        if (l == 0) {
            const float bj = b1[j];
#pragma unroll
            for (int g = 0; g < 8; ++g)
                zz[(long)(g0 + g) * 600 + j] = fmaxf(s[g] + bj, 0.f);
        }
    }
}

__global__ __launch_bounds__(64) void k_lin2(const float* __restrict__ zz,
                                             const float* __restrict__ w2,
                                             const float* __restrict__ b2,
                                             float* __restrict__ out) {
    int g = blockIdx.x;
    int l = threadIdx.x;
    float p[NC];
#pragma unroll
    for (int c = 0; c < NC; ++c) p[c] = 0.f;
    for (int k = l; k < 600; k += 64) {
        float zv = zz[(long)g * 600 + k];
#pragma unroll
        for (int c = 0; c < NC; ++c) p[c] = fmaf(zv, w2[c * 600 + k], p[c]);
    }
#pragma unroll
    for (int c = 0; c < NC; ++c)
#pragma unroll
        for (int o = 32; o; o >>= 1) p[c] += __shfl_xor(p[c], o);
    if (l == 0) {
        float lg[NC];
        float mx = -1e30f;
#pragma unroll
        for (int c = 0; c < NC; ++c) { lg[c] = p[c] + b2[c]; mx = fmaxf(mx, lg[c]); }
        float se = 0.f;
#pragma unroll
        for (int c = 0; c < NC; ++c) se += expf(lg[c] - mx);
        float lse = logf(se);
#pragma unroll
        for (int c = 0; c < NC; ++c) out[(long)g * NC + c] = lg[c] - mx - lse;
    }
}

// ---------------- launch ----------------

extern "C" void kernel_launch(void* const* d_in, const int* in_sizes, int n_in,
                              void* d_out, int out_size, void* d_ws, size_t ws_size,
                              hipStream_t stream) {
    const float* x      = (const float*)d_in[0];
    const int*   ei     = (const int*)d_in[1];
    const int*   batch  = (const int*)d_in[2];
    const float* c0_w1  = (const float*)d_in[4];
    const float* c0_b1  = (const float*)d_in[5];
    const float* c0_g1  = (const float*)d_in[6];
    const float* c0_be1 = (const float*)d_in[7];
    const float* c0_w2  = (const float*)d_in[8];
    const float* c0_b2  = (const float*)d_in[9];
    const float* c0_g2  = (const float*)d_in[10];
    const float* c0_be2 = (const float*)d_in[11];
    const float* c0_w3  = (const float*)d_in[12];
    const float* c0_b3  = (const float*)d_in[13];
    const float* cw1    = (const float*)d_in[14];
    const float* cb1    = (const float*)d_in[15];
    const float* cg1    = (const float*)d_in[16];
    const float* cbe1   = (const float*)d_in[17];
    const float* cw2    = (const float*)d_in[18];
    const float* cb2    = (const float*)d_in[19];
    const float* cg2    = (const float*)d_in[20];
    const float* cbe2   = (const float*)d_in[21];
    const float* cw3    = (const float*)d_in[22];
    const float* cb3    = (const float*)d_in[23];
    const float* lin1_w = (const float*)d_in[24];
    const float* lin1_b = (const float*)d_in[25];
    const float* lin2_w = (const float*)d_in[26];
    const float* lin2_b = (const float*)d_in[27];

    const int* src = ei;
    const int* dst = ei + NE;

    char* ws = (char*)d_ws;
    size_t off = 0;
    auto alloc = [&](size_t bytes) {
        void* p = ws + off;
        off += (bytes + 255) & ~(size_t)255;
        return p;
    };
    u16*   bufh   = (u16*)alloc((size_t)NN * H * 2 + 128);   // K-tail overread pad
    u16*   bufa   = (u16*)alloc((size_t)NN * H * 2 + 128);
    float* agg0   = (float*)alloc((size_t)NN * 4 * 4);
    // ---- contiguous zero region: deg | statsA | mom | pf | cnt ----
    char*  zstart = ws + off;
    int*   deg    = (int*)alloc((size_t)NN * 4);
    float* statsA = (float*)alloc((size_t)6 * SSLOT * 4);
    float* mom    = (float*)alloc(14 * 4);
    float* pf     = (float*)alloc((size_t)3 * NG * 400 * 4);
    int*   cnt    = (int*)alloc((size_t)NG * 4);
    size_t zbytes = (size_t)((ws + off) - zstart);
    // ---- rest ----
    float* pools  = (float*)alloc((size_t)NG * 3 * H * 4);
    float* zz     = (float*)alloc((size_t)NG * 600 * 4);
    float* bb1    = (float*)alloc(400 * 4);
    float* bb2    = (float*)alloc(400 * 4);
    u16*   wpad   = (u16*)alloc((size_t)5 * 400 * KP * 2);
    int*   rowp   = (int*)alloc((size_t)(NN + 1) * 4);
    int*   cur    = (int*)alloc((size_t)NN * 4);
    int*   csrc   = (int*)alloc((size_t)NE * 4);
    int*   part   = (int*)alloc((size_t)NN * 4);
    int*   btot   = (int*)alloc((size_t)NB1 * 4);

    auto wp   = [&](int mat) { return wpad + (size_t)mat * 400 * KP; };
    auto slot = [&](int i)   { return statsA + (size_t)i * SSLOT; };

    hipMemsetAsync(zstart, 0, zbytes, stream);

    k_wprep<<<346, 256, 0, stream>>>(c0_w2, cw2, cw1, c0_w3, cw3, c0_b3, cb3,
                                     wpad, bb1, bb2);

    // CSR build + graph counts
    k_count<<<(NE + 255) / 256, 256, 0, stream>>>(dst, deg);
    k_scan1<<<NB1, 256, 0, stream>>>(deg, part, btot);
    k_scan2<<<1, 256, 0, stream>>>(btot);
    k_scan3<<<NB1, 256, 0, stream>>>(part, btot, deg, rowp, cur, batch, cnt);
    k_scatter<<<(NE + 255) / 256, 256, 0, stream>>>(src, dst, cur, csrc);

    const int ngemm = ((NN + 127) / 128) * 5;   // 1955 blocks

    // layer 0: agg0(+moments) -> lin0(+analytic stats); z2 -> y2; pool via pf[0]
    k_agg0<<<NB1, 256, 0, stream>>>(x, rowp, csrc, agg0, mom);
    k_lin0<<<NLIN0 + 2, 256, 0, stream>>>(agg0, c0_w1, c0_b1, bufh, mom, slot(0));
    gemm_mfma<true><<<ngemm, 256, 0, stream>>>(bufh, wp(0), c0_b2, c0_g1, c0_be1,
                                               slot(0), slot(1), bufa, NN);         // z2
    gemm_mfma<false><<<ngemm, 256, 0, stream>>>(bufa, wp(3), bb1, c0_g2, c0_be2,
                                                slot(1), nullptr, bufh, NN);        // y2
    k_poolf<<<512, 256, 0, stream>>>(bufa, slot(1), c0_g2, c0_be2, batch, pf);

    // layer 1
    k_aggH<<<(NN + 3) / 4, 256, 0, stream>>>(bufh, rowp, csrc, cb1, bufa);          // z1'
    k_statsv<<<256, 256, 0, stream>>>(bufa, slot(2));
    gemm_mfma<true><<<ngemm, 256, 0, stream>>>(bufa, wp(1), cb2, cg1, cbe1,
                                               slot(2), slot(3), bufh, NN);         // z2'
    gemm_mfma<false><<<ngemm, 256, 0, stream>>>(bufh, wp(4), bb2, cg2, cbe2,
                                                slot(3), nullptr, bufa, NN);        // y2'
    k_poolf<<<512, 256, 0, stream>>>(bufh, slot(3), cg2, cbe2, batch, pf + (size_t)NG * 400);

    // layer 2
    k_aggH<<<(NN + 3) / 4, 256, 0, stream>>>(bufa, rowp, csrc, cb1 + 400, bufh);    // z1''
    k_statsv<<<256, 256, 0, stream>>>(bufh, slot(4));
    gemm_mfma<true><<<ngemm, 256, 0, stream>>>(bufh, wp(2), cb2 + 400, cg1 + 400,
                                               cbe1 + 400, slot(4), slot(5), bufa, NN); // z2''
    k_poolf<<<512, 256, 0, stream>>>(bufa, slot(5), cg2 + 400, cbe2 + 400, batch,
                                     pf + (size_t)2 * NG * 400);

    // pools = pf * W3^T + cnt*b3, then readout
    dim3 gp(NG, 3);
    k_poolgemm<<<gp, 256, 0, stream>>>(pf, c0_w3, cw3, c0_b3, cb3, cnt, pools);
    dim3 gl1(15, 16);
    k_lin1<<<gl1, 256, 0, stream>>>(pools, lin1_w, lin1_b, zz);
    k_lin2<<<NG, 64, 0, stream>>>(zz, lin2_w, lin2_b, (float*)d_out);
}

// Round 20
// 733.401 us; speedup vs baseline: 1.0843x; 1.0249x over previous
//
#include <hip/hip_runtime.h>
#include <hip/hip_bf16.h>
#include <math.h>
#include <cstdint>

static constexpr int NN = 50000;   // nodes
static constexpr int NE = 400000;  // edges
static constexpr int H  = 400;     // hidden dim
static constexpr int NG = 128;     // graphs
static constexpr int NC = 10;      // classes
static constexpr float EPS = 1e-5f;
static constexpr int NB1 = (NN + 255) / 256;   // 196 scan blocks
static constexpr int KP  = 416;                // padded K for weights
static constexpr int SREP = 8;                 // stats replicas (contention spread)
static constexpr int SSLOT = SREP * 2 * KP;    // floats per stats slot
static constexpr int NWGG = ((NN + 127) / 128) * 5;   // 1955 gemm blocks
static constexpr int PBLK = 512;               // fused poolf tail blocks

typedef unsigned short u16;
typedef __attribute__((ext_vector_type(8))) unsigned short u16x8;
typedef __attribute__((ext_vector_type(4))) unsigned short u16x4;
typedef __attribute__((ext_vector_type(8))) short bf16x8;
typedef __attribute__((ext_vector_type(4))) float f32x4;

__device__ __forceinline__ float bf2f(u16 u) {
    return __uint_as_float(((uint32_t)u) << 16);
}
__device__ __forceinline__ u16 f2bf(float f) {
    uint32_t u = __float_as_uint(f);
    return (u16)((u + 0x7FFFu + ((u >> 16) & 1u)) >> 16);
}
__device__ __forceinline__ void gload_lds16(const void* g, void* lds) {
    __builtin_amdgcn_global_load_lds((const __attribute__((address_space(1))) void*)g,
                                     (__attribute__((address_space(3))) void*)lds, 16, 0, 0);
}

// BN+ReLU on a bf16x8 fragment using HW packed bf16 convert
__device__ __forceinline__ bf16x8 bnrelu8(bf16x8 a, const float* __restrict__ scp,
                                          const float* __restrict__ shp) {
    union { bf16x8 v; uint32_t u[4]; } in, out;
    in.v = a;
#pragma unroll
    for (int p = 0; p < 4; ++p) {
        float lo = __uint_as_float(in.u[p] << 16);
        float hi = __uint_as_float(in.u[p] & 0xFFFF0000u);
        lo = fmaxf(fmaf(lo, scp[2 * p], shp[2 * p]), 0.f);
        hi = fmaxf(fmaf(hi, scp[2 * p + 1], shp[2 * p + 1]), 0.f);
        asm("v_cvt_pk_bf16_f32 %0, %1, %2" : "=v"(out.u[p]) : "v"(lo), "v"(hi));
    }
    return out.v;
}

// ---------------- CSR build ----------------

__global__ void k_count(const int* __restrict__ dst, int* __restrict__ deg) {
    int e = blockIdx.x * blockDim.x + threadIdx.x;
    if (e < NE) atomicAdd(&deg[dst[e]], 1);
}

__global__ __launch_bounds__(256) void k_scan1(const int* __restrict__ deg,
                                               int* __restrict__ part,
                                               int* __restrict__ btot) {
    __shared__ int sd[256];
    int t = threadIdx.x;
    int i = blockIdx.x * 256 + t;
    int v = (i < NN) ? deg[i] : 0;
    sd[t] = v;
    __syncthreads();
#pragma unroll
    for (int off = 1; off < 256; off <<= 1) {
        int x = (t >= off) ? sd[t - off] : 0;
        __syncthreads();
        sd[t] += x;
        __syncthreads();
    }
    if (i < NN) part[i] = sd[t];
    if (t == 255) btot[blockIdx.x] = sd[255];
}

// scan3: own prefix over raw btot + rowp/cur + graph counts (scan2 eliminated)
__global__ __launch_bounds__(256) void k_scan3(const int* __restrict__ part,
                                               const int* __restrict__ btot,
                                               const int* __restrict__ deg,
                                               int* __restrict__ rowp,
                                               int* __restrict__ cur,
                                               const int* __restrict__ batch,
                                               int* __restrict__ cnt) {
    __shared__ int hh[NG];
    __shared__ int ws4[4];
    int t = threadIdx.x;
    int i = blockIdx.x * 256 + t;
    // base = sum of raw block totals before this block
    int partial = 0;
    for (int j = t; j < (int)blockIdx.x; j += 256) partial += btot[j];
#pragma unroll
    for (int o = 32; o; o >>= 1) partial += __shfl_xor(partial, o);
    if ((t & 63) == 0) ws4[t >> 6] = partial;
    for (int j = t; j < NG; j += 256) hh[j] = 0;
    __syncthreads();
    int base = ws4[0] + ws4[1] + ws4[2] + ws4[3];
    if (i < NN) {
        int s = part[i] + base;
        rowp[i + 1] = s;
        cur[i] = s - deg[i];
        atomicAdd(&hh[batch[i]], 1);
    }
    if (i == 0) rowp[0] = 0;
    __syncthreads();
    for (int j = t; j < NG; j += 256)
        if (hh[j]) atomicAdd(&cnt[j], hh[j]);
}

__global__ void k_scatter(const int* __restrict__ src, const int* __restrict__ dst,
                          int* __restrict__ cur, int* __restrict__ csrc) {
    int e = blockIdx.x * blockDim.x + threadIdx.x;
    if (e < NE) {
        int d = dst[e];
        int p = atomicAdd(&cur[d], 1);
        csrc[p] = src[e];
    }
}

// ---------------- unified weight prep: cvt x3 | merge x2 | bias x2 (flat grid) ----------------

__global__ __launch_bounds__(256) void k_wprep(const float* __restrict__ c0_w2,
                                               const float* __restrict__ cw2,
                                               const float* __restrict__ cw1,
                                               const float* __restrict__ c0_w3,
                                               const float* __restrict__ cw3,
                                               const float* __restrict__ c0_b3,
                                               const float* __restrict__ cb3,
                                               u16* __restrict__ wpad,
                                               float* __restrict__ bb1,
                                               float* __restrict__ bb2) {
    const int b = blockIdx.x;
    const int t = threadIdx.x;
    if (b < 244) {
        int i = b * 256 + t;   // over 3*400*52
        if (i >= 3 * 400 * 52) return;
        int rc = i / 52;
        int c8 = (i % 52) * 8;
        u16x8 o = {0, 0, 0, 0, 0, 0, 0, 0};
        if (c8 < 400) {
            int mat = rc / 400, row = rc % 400;
            const float* s = (mat == 0 ? c0_w2 : mat == 1 ? cw2 : cw2 + 160000)
                             + (long)row * 400;
            float4 a = *(const float4*)(s + c8);
            float4 bb = *(const float4*)(s + c8 + 4);
            o[0] = f2bf(a.x); o[1] = f2bf(a.y); o[2] = f2bf(a.z); o[3] = f2bf(a.w);
            o[4] = f2bf(bb.x); o[5] = f2bf(bb.y); o[6] = f2bf(bb.z); o[7] = f2bf(bb.w);
        }
        *(u16x8*)(wpad + (long)rc * KP + c8) = o;
    } else if (b < 342) {
        __shared__ float As[16][68];
        __shared__ float Bs[16][68];
        const int b2 = (b < 293) ? b - 244 : b - 293;
        const float* Wa = (b < 293) ? cw1 : cw1 + 160000;
        const float* Wb = (b < 293) ? c0_w3 : cw3;
        u16* dst = wpad + (size_t)((b < 293) ? 3 : 4) * 400 * KP;
        const int bc = (b2 / 7) * 64, bj = (b2 % 7) * 64;
        const int tx = t & 15, ty = t >> 4;
        float acc[4][4] = {};
        for (int k0 = 0; k0 < 400; k0 += 16) {
            {
                int c = bc + (t >> 2);
                int kq = (t & 3) * 4;
                float4 v = make_float4(0.f, 0.f, 0.f, 0.f);
                if (c < 400) v = *(const float4*)(Wa + (long)c * 400 + k0 + kq);
                As[kq + 0][t >> 2] = v.x; As[kq + 1][t >> 2] = v.y;
                As[kq + 2][t >> 2] = v.z; As[kq + 3][t >> 2] = v.w;
            }
            {
                int k = k0 + (t >> 4);
                int jq = (t & 15) * 4;
                int j = bj + jq;
                float4 v = make_float4(0.f, 0.f, 0.f, 0.f);
                if (j < 400) v = *(const float4*)(Wb + (long)k * 400 + j);
                Bs[t >> 4][jq + 0] = v.x; Bs[t >> 4][jq + 1] = v.y;
                Bs[t >> 4][jq + 2] = v.z; Bs[t >> 4][jq + 3] = v.w;
            }
            __syncthreads();
#pragma unroll
            for (int kk = 0; kk < 16; ++kk) {
                float4 av = *(const float4*)&As[kk][ty * 4];
                float4 bv = *(const float4*)&Bs[kk][tx * 4];
                float a[4] = {av.x, av.y, av.z, av.w};
                float bb[4] = {bv.x, bv.y, bv.z, bv.w};
#pragma unroll
                for (int i = 0; i < 4; ++i)
#pragma unroll
                    for (int j = 0; j < 4; ++j)
                        acc[i][j] = fmaf(a[i], bb[j], acc[i][j]);
            }
            __syncthreads();
        }
#pragma unroll
        for (int i = 0; i < 4; ++i) {
            int c = bc + ty * 4 + i;
            if (c >= 400) continue;
#pragma unroll
            for (int j = 0; j < 4; ++j) {
                int col = bj + tx * 4 + j;
                if (col < KP) dst[(long)c * KP + col] = (col < 400) ? f2bf(acc[i][j]) : 0;
            }
        }
    } else {
        const int c = (b & 1) * 256 + t;
        if (c >= 400) return;
        const float* Wa = (b < 344) ? cw1 : cw1 + 160000;
        const float* bv = (b < 344) ? c0_b3 : cb3;
        float* out = (b < 344) ? bb1 : bb2;
        const float4* wr = (const float4*)(Wa + (long)c * 400);
        const float4* br = (const float4*)bv;
        float s0 = 0.f, s1 = 0.f, s2 = 0.f, s3 = 0.f;
        for (int q = 0; q < 100; ++q) {
            float4 a = wr[q], v = br[q];
            s0 = fmaf(a.x, v.x, s0); s1 = fmaf(a.y, v.y, s1);
            s2 = fmaf(a.z, v.z, s2); s3 = fmaf(a.w, v.w, s3);
        }
        out[c] = s0 + s1 + s2 + s3;
    }
}

// ---------------- agg0 + moments ----------------

__global__ __launch_bounds__(256) void k_agg0(const float* __restrict__ x,
                                              const int* __restrict__ rowp,
                                              const int* __restrict__ csrc,
                                              float* __restrict__ out,
                                              float* __restrict__ mom) {
    __shared__ float ws[4][14];
    int n = blockIdx.x * blockDim.x + threadIdx.x;
    float4 acc = make_float4(0.f, 0.f, 0.f, 0.f);
    if (n < NN) {
        int b = rowp[n], e = rowp[n + 1];
        for (int p = b; p < e; ++p) {
            float4 v = ((const float4*)x)[csrc[p]];
            acc.x += v.x; acc.y += v.y; acc.z += v.z; acc.w += v.w;
        }
        ((float4*)out)[n] = acc;
    }
    float mv[14] = {acc.x, acc.y, acc.z, acc.w,
                    acc.x * acc.x, acc.x * acc.y, acc.x * acc.z, acc.x * acc.w,
                    acc.y * acc.y, acc.y * acc.z, acc.y * acc.w,
                    acc.z * acc.z, acc.z * acc.w, acc.w * acc.w};
    int wv = threadIdx.x >> 6, l = threadIdx.x & 63;
#pragma unroll
    for (int i = 0; i < 14; ++i) {
        float s = mv[i];
#pragma unroll
        for (int o = 32; o; o >>= 1) s += __shfl_xor(s, o);
        if (l == 0) ws[wv][i] = s;
    }
    __syncthreads();
    if (threadIdx.x < 14) {
        float s = ws[0][threadIdx.x] + ws[1][threadIdx.x] + ws[2][threadIdx.x] + ws[3][threadIdx.x];
        atomicAdd(&mom[threadIdx.x], s);
    }
}

// ---------------- aggH: one wave per node (latency-optimal) ----------------

__global__ __launch_bounds__(256) void k_aggH(const u16* __restrict__ h,
                                              const int* __restrict__ rowp,
                                              const int* __restrict__ csrc,
                                              const float* __restrict__ bias,
                                              u16* __restrict__ out) {
    int n = (blockIdx.x << 2) + (threadIdx.x >> 6);
    if (n >= NN) return;
    int l = threadIdx.x & 63;
    if (l >= 50) return;
    float4 b0 = *(const float4*)(bias + l * 8);
    float4 b1 = *(const float4*)(bias + l * 8 + 4);
    float acc[8] = {b0.x, b0.y, b0.z, b0.w, b1.x, b1.y, b1.z, b1.w};
    int b = rowp[n], e = rowp[n + 1];
    for (int p = b; p < e; ++p) {
        const u16* r = h + (long)csrc[p] * H + l * 8;
        u16x8 v = *(const u16x8*)r;
#pragma unroll
        for (int q = 0; q < 8; ++q) acc[q] += bf2f(v[q]);
    }
    u16x8 o;
#pragma unroll
    for (int q = 0; q < 8; ++q) o[q] = f2bf(acc[q]);
    *(u16x8*)(out + (long)n * H + l * 8) = o;
}

// ---------------- first linear (K = 4) + fused analytic z1 stats ----------------

static constexpr int NLIN0 = (int)(((long)NN * 100 + 255) / 256);

__global__ void k_lin0(const float* __restrict__ a4, const float* __restrict__ w,
                       const float* __restrict__ b, u16* __restrict__ out,
                       const float* __restrict__ mom, float* __restrict__ slot0) {
    if (blockIdx.x >= NLIN0) {
        int j = (blockIdx.x - NLIN0) * 256 + threadIdx.x;
        if (j >= 400) return;
        float4 wv = ((const float4*)w)[j];
        float dot = wv.x * mom[0] + wv.y * mom[1] + wv.z * mom[2] + wv.w * mom[3];
        float quad = wv.x * wv.x * mom[4] + 2.f * wv.x * wv.y * mom[5]
                   + 2.f * wv.x * wv.z * mom[6] + 2.f * wv.x * wv.w * mom[7]
                   + wv.y * wv.y * mom[8] + 2.f * wv.y * wv.z * mom[9]
                   + 2.f * wv.y * wv.w * mom[10] + wv.z * wv.z * mom[11]
                   + 2.f * wv.z * wv.w * mom[12] + wv.w * wv.w * mom[13];
        float bj = b[j];
        slot0[j] = dot + (float)NN * bj;
        slot0[KP + j] = quad + 2.f * bj * dot + (float)NN * bj * bj;
        return;
    }
    long i = (long)blockIdx.x * blockDim.x + threadIdx.x;
    if (i >= (long)NN * 100) return;
    int n = (int)(i / 100), q = (int)(i - (long)n * 100);
    int j0 = q * 4;
    float4 av = ((const float4*)a4)[n];
    u16x4 o;
#pragma unroll
    for (int jj = 0; jj < 4; ++jj) {
        float4 wv = ((const float4*)w)[j0 + jj];
        float s = fmaf(av.x, wv.x, fmaf(av.y, wv.y, fmaf(av.z, wv.z, av.w * wv.w)));
        o[jj] = f2bf(s + b[j0 + jj]);
    }
    *(u16x4*)(out + (long)n * H + j0) = o;
}

// ---------------- BN stats over bf16 buffer -> replica slot ----------------

__global__ __launch_bounds__(256) void k_statsv(const u16* __restrict__ z,
                                                float* __restrict__ stats) {
    __shared__ float ls[800];
    int t = threadIdx.x;
    for (int i = t; i < 800; i += 256) ls[i] = 0.f;
    __syncthreads();
    if (t < 250) {
        int sub = t / 50, seg = t % 50;
        float s[8] = {0, 0, 0, 0, 0, 0, 0, 0};
        float q[8] = {0, 0, 0, 0, 0, 0, 0, 0};
        for (int r = blockIdx.x * 5 + sub; r < NN; r += gridDim.x * 5) {
            u16x8 v = *(const u16x8*)(z + (long)r * H + seg * 8);
#pragma unroll
            for (int j = 0; j < 8; ++j) {
                float f = bf2f(v[j]);
                s[j] += f; q[j] += f * f;
            }
        }
#pragma unroll
        for (int j = 0; j < 8; ++j) {
            atomicAdd(&ls[seg * 8 + j], s[j]);
            atomicAdd(&ls[400 + seg * 8 + j], q[j]);
        }
    }
    __syncthreads();
    const int rep = blockIdx.x & (SREP - 1);
    for (int i = t; i < 800; i += 256) {
        int col = (i < 400) ? i : (i - 400 + KP);
        atomicAdd(&stats[rep * 2 * KP + col], ls[i]);
    }
}

// ---------------- MFMA GEMM (R17 structure) + optional fused poolf tail blocks ----------------
// Blocks [0, NWGG): GEMM with fused BN-finalize + BN/ReLU + optional stats.
// POOL: blocks [NWGG, NWGG+PBLK) run the pooled-f2 reduction over A (same input,
// same BN stats) -> pf; they overlap the GEMM's tail.

template <bool STATS, bool POOL>
__global__ __launch_bounds__(256) void gemm_mfma(const u16* __restrict__ A,
                                                 const u16* __restrict__ Wp,
                                                 const float* __restrict__ bias,
                                                 const float* __restrict__ bnG,
                                                 const float* __restrict__ bnBe,
                                                 const float* __restrict__ statsIn,
                                                 float* __restrict__ statsOut,
                                                 u16* __restrict__ out,
                                                 const int* __restrict__ batch,
                                                 float* __restrict__ pf, int M) {
    constexpr int BUF = 6656;            // u16 per buffer: A 4096 + B 2560
    __shared__ u16 lds[3 * BUF];         // 39,936 B
    __shared__ float sdScale[KP];
    __shared__ float sdShift[KP];
    __shared__ float sst[160];

    const int t = threadIdx.x;

    if (POOL && blockIdx.x >= NWGG) {
        // ---- fused poolf tail block ----
        const int pb = blockIdx.x - NWGG;
        for (int j = t; j < 400; j += 256) {
            float s = 0.f, q = 0.f;
#pragma unroll
            for (int r = 0; r < SREP; ++r) {
                s += statsIn[r * 2 * KP + j];
                q += statsIn[r * 2 * KP + KP + j];
            }
            float m = s / NN, v = fmaxf(q / NN - m * m, 0.f);
            float rs = rsqrtf(v + EPS);
            float sc = bnG[j] * rs;
            sdScale[j] = sc;
            sdShift[j] = bnBe[j] - m * sc;
        }
        __syncthreads();
        if (t >= 250) return;
        const int sub = t / 50, seg = t % 50;
        float sc[8], sh[8];
#pragma unroll
        for (int q = 0; q < 8; ++q) {
            sc[q] = sdScale[seg * 8 + q];
            sh[q] = sdShift[seg * 8 + q];
        }
        int rows = (NN + PBLK - 1) / PBLK;
        int r0 = pb * rows;
        int r1 = min(r0 + rows, NN);
        float acc[8] = {0.f, 0.f, 0.f, 0.f, 0.f, 0.f, 0.f, 0.f};
        int gp = -1;
        for (int r = r0 + sub; r < r1; r += 5) {
            int gg = batch[r];
            if (gg != gp) {
                if (gp >= 0) {
#pragma unroll
                    for (int q = 0; q < 8; ++q)
                        atomicAdd(&pf[(long)gp * 400 + seg * 8 + q], acc[q]);
                }
#pragma unroll
                for (int q = 0; q < 8; ++q) acc[q] = 0.f;
                gp = gg;
            }
            u16x8 v = *(const u16x8*)(A + (long)r * H + seg * 8);
#pragma unroll
            for (int q = 0; q < 8; ++q)
                acc[q] += fmaxf(fmaf(bf2f(v[q]), sc[q], sh[q]), 0.f);
        }
        if (gp >= 0) {
#pragma unroll
            for (int q = 0; q < 8; ++q)
                atomicAdd(&pf[(long)gp * 400 + seg * 8 + q], acc[q]);
        }
        return;
    }

    // bijective XCD swizzle over the NWGG gemm blocks (1955, not divisible by 8)
    const int q8 = NWGG >> 3, r8 = NWGG & 7;
    const int xcd = blockIdx.x & 7, jj = blockIdx.x >> 3;
    const int wgid = (xcd < r8 ? xcd * (q8 + 1) : r8 * (q8 + 1) + (xcd - r8) * q8) + jj;
    const int bm = (wgid / 5) * 128;
    const int bn = (wgid % 5) * 80;
    const int w = t >> 6, l = t & 63;

    // ---- BN finalize prologue ----
    for (int j = t; j < KP; j += 256) {
        float s = 0.f, q = 0.f;
#pragma unroll
        for (int r = 0; r < SREP; ++r) {
            s += statsIn[r * 2 * KP + j];
            q += statsIn[r * 2 * KP + KP + j];
        }
        float sc = 0.f, sh = 0.f;
        if (j < H) {
            float m = s / NN;
            float v = fmaxf(q / NN - m * m, 0.f);
            float rs = rsqrtf(v + EPS);
            sc = bnG[j] * rs;
            sh = bnBe[j] - m * sc;
        }
        sdScale[j] = sc;
        sdShift[j] = sh;
    }

    const int srow = l >> 2;
    const int sck  = ((l & 3) ^ ((l >> 3) & 3)) * 8;   // source-side XOR swizzle

    auto stageTile = [&](int b, int kt) {
        u16* dst = lds + b * BUF;
        const int k0 = kt * 32;
        long g0 = (long)bm + w * 16 + srow;
        long g1 = g0 + 64;
        if (g0 > M - 1) g0 = M - 1;
        if (g1 > M - 1) g1 = M - 1;
        gload_lds16(A + g0 * 400 + k0 + sck, dst + w * 512);
        gload_lds16(A + g1 * 400 + k0 + sck, dst + (w + 4) * 512);
        gload_lds16(Wp + (long)(bn + w * 16 + srow) * KP + k0 + sck,
                    dst + 4096 + w * 512);
        gload_lds16(Wp + (long)(bn + 64 + srow) * KP + k0 + sck,
                    dst + 4096 + 4 * 512);       // B seg 4 (x4 dup -> uniform 4 loads/wave)
    };

    f32x4 acc[2][5];
#pragma unroll
    for (int i = 0; i < 2; ++i)
#pragma unroll
        for (int c = 0; c < 5; ++c)
            acc[i][c] = (f32x4){0.f, 0.f, 0.f, 0.f};

    const int r16 = l & 15;
    const int cc  = l >> 4;
    const int swz = r16 * 32 + (((cc ^ ((r16 >> 1) & 3))) << 3);

    auto computeTile = [&](int b, int s) {
        const u16* base = lds + b * BUF;
        const u16* ab = base + w * 1024 + swz;
        const u16* bb = base + 4096 + swz;
        bf16x8 fa0 = *(const bf16x8*)ab;
        bf16x8 fa1 = *(const bf16x8*)(ab + 512);
        const int k = s * 32 + cc * 8;
        fa0 = bnrelu8(fa0, sdScale + k, sdShift + k);
        fa1 = bnrelu8(fa1, sdScale + k, sdShift + k);
        __builtin_amdgcn_s_setprio(1);
#pragma unroll
        for (int c = 0; c < 5; ++c) {
            bf16x8 fb = *(const bf16x8*)(bb + c * 512);
            acc[0][c] = __builtin_amdgcn_mfma_f32_16x16x32_bf16(fa0, fb, acc[0][c], 0, 0, 0);
            acc[1][c] = __builtin_amdgcn_mfma_f32_16x16x32_bf16(fa1, fb, acc[1][c], 0, 0, 0);
        }
        __builtin_amdgcn_s_setprio(0);
    };

    // prologue: tiles 0,1 in flight (8 loads/wave)
    stageTile(0, 0);
    stageTile(1, 1);

#pragma unroll 1
    for (int s = 0; s < 12; ++s) {
        asm volatile("s_waitcnt vmcnt(4)" ::: "memory");
        __builtin_amdgcn_s_barrier();
        if (s + 2 < 13) stageTile((s + 2) % 3, s + 2);
        computeTile(s % 3, s);
    }
    asm volatile("s_waitcnt vmcnt(0)" ::: "memory");
    __builtin_amdgcn_s_barrier();
    computeTile(12 % 3, 12);

    // ---- epilogue: LDS-bounced coalesced stores + fused stats ----
    u16* tile = lds;
    __syncthreads();
    if (STATS) for (int i = t; i < 160; i += 256) sst[i] = 0.f;
    if (STATS) __syncthreads();

    float ssum[5], sqq[5];
#pragma unroll
    for (int c = 0; c < 5; ++c) { ssum[c] = 0.f; sqq[c] = 0.f; }
#pragma unroll
    for (int i = 0; i < 2; ++i) {
        const int lrow0 = w * 32 + i * 16 + (l >> 4) * 4;
#pragma unroll
        for (int c = 0; c < 5; ++c) {
            const int lcol = c * 16 + (l & 15);
            const float bv = bias[bn + lcol];
#pragma unroll
            for (int r = 0; r < 4; ++r) {
                const int lrow = lrow0 + r;
                float z = acc[i][c][r] + bv;
                tile[lrow * 80 + lcol] = f2bf(z);
                if (STATS && bm + lrow < M) { ssum[c] += z; sqq[c] += z * z; }
            }
        }
    }
    __syncthreads();
#pragma unroll
    for (int j = 0; j < 5; ++j) {
        int chunk = t + j * 256;
        int row = chunk / 10, c8 = chunk % 10;
        if (bm + row < M) {
            u16x8 v = *(const u16x8*)(tile + row * 80 + c8 * 8);
            *(u16x8*)(out + (long)(bm + row) * H + bn + c8 * 8) = v;
        }
    }
    if (STATS) {
        const int rep = wgid & (SREP - 1);
#pragma unroll
        for (int c = 0; c < 5; ++c) {
            ssum[c] += __shfl_xor(ssum[c], 16); ssum[c] += __shfl_xor(ssum[c], 32);
            sqq[c]  += __shfl_xor(sqq[c], 16);  sqq[c]  += __shfl_xor(sqq[c], 32);
        }
        if (l < 16) {
#pragma unroll
            for (int c = 0; c < 5; ++c) {
                atomicAdd(&sst[c * 16 + l], ssum[c]);
                atomicAdd(&sst[80 + c * 16 + l], sqq[c]);
            }
        }
        __syncthreads();
        if (t < 80)       atomicAdd(&statsOut[rep * 2 * KP + bn + t], sst[t]);
        else if (t < 160) atomicAdd(&statsOut[rep * 2 * KP + KP + bn + (t - 80)], sst[t]);
    }
}

// ---------------- standalone poolf (layer 2 only) ----------------

__global__ __launch_bounds__(256) void k_poolf(const u16* __restrict__ z,
                                               const float* __restrict__ statsIn,
                                               const float* __restrict__ gw,
                                               const float* __restrict__ be,
                                               const int* __restrict__ batch,
                                               float* __restrict__ pf) {
    __shared__ float sdS[400];
    __shared__ float sdH[400];
    int t = threadIdx.x;
    for (int j = t; j < 400; j += 256) {
        float s = 0.f, q = 0.f;
#pragma unroll
        for (int r = 0; r < SREP; ++r) {
            s += statsIn[r * 2 * KP + j];
            q += statsIn[r * 2 * KP + KP + j];
        }
        float m = s / NN, v = fmaxf(q / NN - m * m, 0.f);
        float rs = rsqrtf(v + EPS);
        float sc = gw[j] * rs;
        sdS[j] = sc;
        sdH[j] = be[j] - m * sc;
    }
    __syncthreads();
    if (t >= 250) return;
    const int sub = t / 50, seg = t % 50;
    float sc[8], sh[8];
#pragma unroll
    for (int q = 0; q < 8; ++q) {
        sc[q] = sdS[seg * 8 + q];
        sh[q] = sdH[seg * 8 + q];
    }
    int rows = (NN + gridDim.x - 1) / gridDim.x;
    int r0 = blockIdx.x * rows;
    int r1 = min(r0 + rows, NN);
    float acc[8] = {0.f, 0.f, 0.f, 0.f, 0.f, 0.f, 0.f, 0.f};
    int gp = -1;
    for (int r = r0 + sub; r < r1; r += 5) {
        int gg = batch[r];
        if (gg != gp) {
            if (gp >= 0) {
#pragma unroll
                for (int q = 0; q < 8; ++q)
                    atomicAdd(&pf[(long)gp * 400 + seg * 8 + q], acc[q]);
            }
#pragma unroll
            for (int q = 0; q < 8; ++q) acc[q] = 0.f;
            gp = gg;
        }
        u16x8 v = *(const u16x8*)(z + (long)r * H + seg * 8);
#pragma unroll
        for (int q = 0; q < 8; ++q)
            acc[q] += fmaxf(fmaf(bf2f(v[q]), sc[q], sh[q]), 0.f);
    }
    if (gp >= 0) {
#pragma unroll
        for (int q = 0; q < 8; ++q)
            atomicAdd(&pf[(long)gp * 400 + seg * 8 + q], acc[q]);
    }
}

// ---------------- pools[g][L*400+c] = pf[L][g]·W3_L[c]ᵀ + cnt[g]*b3_L[c] ----------------

__global__ __launch_bounds__(256) void k_poolgemm(const float* __restrict__ pf,
                                                  const float* __restrict__ w30,
                                                  const float* __restrict__ w312,
                                                  const float* __restrict__ b30,
                                                  const float* __restrict__ b312,
                                                  const int* __restrict__ cnt,
                                                  float* __restrict__ pools) {
    __shared__ __align__(16) float xr[400];
    int g = blockIdx.x, L = blockIdx.y, t = threadIdx.x;
    const float* w = (L == 0) ? w30 : w312 + (size_t)(L - 1) * 400 * 400;
    const float* b = (L == 0) ? b30 : b312 + (L - 1) * 400;
    for (int i = t; i < 400; i += 256) xr[i] = pf[((long)L * NG + g) * 400 + i];
    __syncthreads();
    float cg = (float)cnt[g];
    for (int c = t; c < 400; c += 256) {
        const float4* wr = (const float4*)(w + (long)c * 400);
        const float4* xv = (const float4*)xr;
        float s0 = 0.f, s1 = 0.f, s2 = 0.f, s3 = 0.f;
        for (int q = 0; q < 100; ++q) {
            float4 a = xv[q], bb = wr[q];
            s0 = fmaf(a.x, bb.x, s0); s1 = fmaf(a.y, bb.y, s1);
            s2 = fmaf(a.z, bb.z, s2); s3 = fmaf(a.w, bb.w, s3);
        }
        pools[(long)g * 1200 + L * 400 + c] = s0 + s1 + s2 + s3 + cg * b[c];
    }
}

// ---------------- readout ----------------

__global__ __launch_bounds__(256) void k_lin1(const float* __restrict__ pools,
                                              const float* __restrict__ w1,
                                              const float* __restrict__ b1,
                                              float* __restrict__ zz) {
    __shared__ __align__(16) float xg[8][1200];
    const int bandj = blockIdx.x * 40;
    const int g0 = blockIdx.y * 8;
    const int t = threadIdx.x;
    for (int i = t; i < 9600; i += 256)
        xg[i / 1200][i % 1200] = pools[(long)(g0 + i / 1200) * 1200 + (i % 1200)];
    __syncthreads();
    const int wv = t >> 6, l = t & 63;
    for (int jj = wv; jj < 40; jj += 4) {
        const int j = bandj + jj;
        const float4* wr = (const float4*)(w1 + (long)j * 1200);
        float s[8] = {0.f, 0.f, 0.f, 0.f, 0.f, 0.f, 0.f, 0.f};
        for (int q = l; q < 300; q += 64) {
            float4 wq = wr[q];
#pragma unroll
            for (int g = 0; g < 8; ++g) {
                float4 xv = *(const float4*)&xg[g][q * 4];
                s[g] = fmaf(wq.x, xv.x, s[g]);
                s[g] = fmaf(wq.y, xv.y, s[g]);
                s[g] = fmaf(wq.z, xv.z, s[g]);
                s[g] = fmaf(wq.w, xv.w, s[g]);
            }
        }
#pragma unroll
        for (int g = 0; g < 8; ++g)
#pragma unroll
            for (int o = 32; o; o >>= 1) s[g] += __shfl_xor(s[g], o);
        if (l == 0) {
            const float bj = b1[j];
#pragma unroll
            for (int g = 0; g < 8; ++g)
                zz[(long)(g0 + g) * 600 + j] = fmaxf(s[g] + bj, 0.f);
        }
    }
}

__global__ __launch_bounds__(64) void k_lin2(const float* __restrict__ zz,
                                             const float* __restrict__ w2,
                                             const float* __restrict__ b2,
                                             float* __restrict__ out) {
    int g = blockIdx.x;
    int l = threadIdx.x;
    float p[NC];
#pragma unroll
    for (int c = 0; c < NC; ++c) p[c] = 0.f;
    for (int k = l; k < 600; k += 64) {
        float zv = zz[(long)g * 600 + k];
#pragma unroll
        for (int c = 0; c < NC; ++c) p[c] = fmaf(zv, w2[c * 600 + k], p[c]);
    }
#pragma unroll
    for (int c = 0; c < NC; ++c)
#pragma unroll
        for (int o = 32; o; o >>= 1) p[c] += __shfl_xor(p[c], o);
    if (l == 0) {
        float lg[NC];
        float mx = -1e30f;
#pragma unroll
        for (int c = 0; c < NC; ++c) { lg[c] = p[c] + b2[c]; mx = fmaxf(mx, lg[c]); }
        float se = 0.f;
#pragma unroll
        for (int c = 0; c < NC; ++c) se += expf(lg[c] - mx);
        float lse = logf(se);
#pragma unroll
        for (int c = 0; c < NC; ++c) out[(long)g * NC + c] = lg[c] - mx - lse;
    }
}

// ---------------- launch ----------------

extern "C" void kernel_launch(void* const* d_in, const int* in_sizes, int n_in,
                              void* d_out, int out_size, void* d_ws, size_t ws_size,
                              hipStream_t stream) {
    const float* x      = (const float*)d_in[0];
    const int*   ei     = (const int*)d_in[1];
    const int*   batch  = (const int*)d_in[2];
    const float* c0_w1  = (const float*)d_in[4];
    const float* c0_b1  = (const float*)d_in[5];
    const float* c0_g1  = (const float*)d_in[6];
    const float* c0_be1 = (const float*)d_in[7];
    const float* c0_w2  = (const float*)d_in[8];
    const float* c0_b2  = (const float*)d_in[9];
    const float* c0_g2  = (const float*)d_in[10];
    const float* c0_be2 = (const float*)d_in[11];
    const float* c0_w3  = (const float*)d_in[12];
    const float* c0_b3  = (const float*)d_in[13];
    const float* cw1    = (const float*)d_in[14];
    const float* cb1    = (const float*)d_in[15];
    const float* cg1    = (const float*)d_in[16];
    const float* cbe1   = (const float*)d_in[17];
    const float* cw2    = (const float*)d_in[18];
    const float* cb2    = (const float*)d_in[19];
    const float* cg2    = (const float*)d_in[20];
    const float* cbe2   = (const float*)d_in[21];
    const float* cw3    = (const float*)d_in[22];
    const float* cb3    = (const float*)d_in[23];
    const float* lin1_w = (const float*)d_in[24];
    const float* lin1_b = (const float*)d_in[25];
    const float* lin2_w = (const float*)d_in[26];
    const float* lin2_b = (const float*)d_in[27];

    const int* src = ei;
    const int* dst = ei + NE;

    char* ws = (char*)d_ws;
    size_t off = 0;
    auto alloc = [&](size_t bytes) {
        void* p = ws + off;
        off += (bytes + 255) & ~(size_t)255;
        return p;
    };
    u16*   bufh   = (u16*)alloc((size_t)NN * H * 2 + 128);   // K-tail overread pad
    u16*   bufa   = (u16*)alloc((size_t)NN * H * 2 + 128);
    float* agg0   = (float*)alloc((size_t)NN * 4 * 4);
    // ---- contiguous zero region: deg | statsA | mom | pf | cnt ----
    char*  zstart = ws + off;
    int*   deg    = (int*)alloc((size_t)NN * 4);
    float* statsA = (float*)alloc((size_t)6 * SSLOT * 4);
    float* mom    = (float*)alloc(14 * 4);
    float* pf     = (float*)alloc((size_t)3 * NG * 400 * 4);
    int*   cnt    = (int*)alloc((size_t)NG * 4);
    size_t zbytes = (size_t)((ws + off) - zstart);
    // ---- rest ----
    float* pools  = (float*)alloc((size_t)NG * 3 * H * 4);
    float* zz     = (float*)alloc((size_t)NG * 600 * 4);
    float* bb1    = (float*)alloc(400 * 4);
    float* bb2    = (float*)alloc(400 * 4);
    u16*   wpad   = (u16*)alloc((size_t)5 * 400 * KP * 2);
    int*   rowp   = (int*)alloc((size_t)(NN + 1) * 4);
    int*   cur    = (int*)alloc((size_t)NN * 4);
    int*   csrc   = (int*)alloc((size_t)NE * 4);
    int*   part   = (int*)alloc((size_t)NN * 4);
    int*   btot   = (int*)alloc((size_t)NB1 * 4);

    auto wp   = [&](int mat) { return wpad + (size_t)mat * 400 * KP; };
    auto slot = [&](int i)   { return statsA + (size_t)i * SSLOT; };

    hipMemsetAsync(zstart, 0, zbytes, stream);

    k_wprep<<<346, 256, 0, stream>>>(c0_w2, cw2, cw1, c0_w3, cw3, c0_b3, cb3,
                                     wpad, bb1, bb2);

    // CSR build + graph counts (scan2 folded into scan3)
    k_count<<<(NE + 255) / 256, 256, 0, stream>>>(dst, deg);
    k_scan1<<<NB1, 256, 0, stream>>>(deg, part, btot);
    k_scan3<<<NB1, 256, 0, stream>>>(part, btot, deg, rowp, cur, batch, cnt);
    k_scatter<<<(NE + 255) / 256, 256, 0, stream>>>(src, dst, cur, csrc);

    // layer 0: agg0(+moments) -> lin0(+analytic stats); z2 -> y2(+fused pool L0)
    k_agg0<<<NB1, 256, 0, stream>>>(x, rowp, csrc, agg0, mom);
    k_lin0<<<NLIN0 + 2, 256, 0, stream>>>(agg0, c0_w1, c0_b1, bufh, mom, slot(0));
    gemm_mfma<true, false><<<NWGG, 256, 0, stream>>>(
        bufh, wp(0), c0_b2, c0_g1, c0_be1, slot(0), slot(1), bufa, nullptr, nullptr, NN);
    gemm_mfma<false, true><<<NWGG + PBLK, 256, 0, stream>>>(
        bufa, wp(3), bb1, c0_g2, c0_be2, slot(1), nullptr, bufh, batch, pf, NN);

    // layer 1
    k_aggH<<<(NN + 3) / 4, 256, 0, stream>>>(bufh, rowp, csrc, cb1, bufa);          // z1'
    k_statsv<<<256, 256, 0, stream>>>(bufa, slot(2));
    gemm_mfma<true, false><<<NWGG, 256, 0, stream>>>(
        bufa, wp(1), cb2, cg1, cbe1, slot(2), slot(3), bufh, nullptr, nullptr, NN);  // z2'
    gemm_mfma<false, true><<<NWGG + PBLK, 256, 0, stream>>>(
        bufh, wp(4), bb2, cg2, cbe2, slot(3), nullptr, bufa, batch,
        pf + (size_t)NG * 400, NN);                                                  // y2' + pool L1

    // layer 2
    k_aggH<<<(NN + 3) / 4, 256, 0, stream>>>(bufa, rowp, csrc, cb1 + 400, bufh);    // z1''
    k_statsv<<<256, 256, 0, stream>>>(bufh, slot(4));
    gemm_mfma<true, false><<<NWGG, 256, 0, stream>>>(
        bufh, wp(2), cb2 + 400, cg1 + 400, cbe1 + 400, slot(4), slot(5), bufa,
        nullptr, nullptr, NN);                                                       // z2''
    k_poolf<<<512, 256, 0, stream>>>(bufa, slot(5), cg2 + 400, cbe2 + 400, batch,
                                     pf + (size_t)2 * NG * 400);

    // pools = pf * W3^T + cnt*b3, then readout
    dim3 gp(NG, 3);
    k_poolgemm<<<gp, 256, 0, stream>>>(pf, c0_w3, cw3, c0_b3, cb3, cnt, pools);
    dim3 gl1(15, 16);
    k_lin1<<<gl1, 256, 0, stream>>>(pools, lin1_w, lin1_b, zz);
    k_lin2<<<NG, 64, 0, stream>>>(zz, lin2_w, lin2_b, (float*)d_out);
}

// Round 21
// 727.432 us; speedup vs baseline: 1.0932x; 1.0082x over previous
//
#include <hip/hip_runtime.h>
#include <hip/hip_bf16.h>
#include <math.h>
#include <cstdint>

static constexpr int NN = 50000;   // nodes
static constexpr int NE = 400000;  // edges
static constexpr int H  = 400;     // hidden dim
static constexpr int NG = 128;     // graphs
static constexpr int NC = 10;      // classes
static constexpr float EPS = 1e-5f;
static constexpr int NB1 = (NN + 255) / 256;   // 196 scan blocks
static constexpr int KP  = 416;                // padded K for weights
static constexpr int SREP = 8;                 // stats replicas (contention spread)
static constexpr int SSLOT = SREP * 2 * KP;    // floats per stats slot
static constexpr int NWGG = ((NN + 127) / 128) * 5;   // 1955 gemm blocks
static constexpr int PBLK = 512;               // fused poolf blocks (scheduled FIRST)

typedef unsigned short u16;
typedef __attribute__((ext_vector_type(8))) unsigned short u16x8;
typedef __attribute__((ext_vector_type(4))) unsigned short u16x4;
typedef __attribute__((ext_vector_type(8))) short bf16x8;
typedef __attribute__((ext_vector_type(4))) float f32x4;

__device__ __forceinline__ float bf2f(u16 u) {
    return __uint_as_float(((uint32_t)u) << 16);
}
__device__ __forceinline__ u16 f2bf(float f) {
    uint32_t u = __float_as_uint(f);
    return (u16)((u + 0x7FFFu + ((u >> 16) & 1u)) >> 16);
}
__device__ __forceinline__ void gload_lds16(const void* g, void* lds) {
    __builtin_amdgcn_global_load_lds((const __attribute__((address_space(1))) void*)g,
                                     (__attribute__((address_space(3))) void*)lds, 16, 0, 0);
}

// BN+ReLU on a bf16x8 fragment using HW packed bf16 convert
__device__ __forceinline__ bf16x8 bnrelu8(bf16x8 a, const float* __restrict__ scp,
                                          const float* __restrict__ shp) {
    union { bf16x8 v; uint32_t u[4]; } in, out;
    in.v = a;
#pragma unroll
    for (int p = 0; p < 4; ++p) {
        float lo = __uint_as_float(in.u[p] << 16);
        float hi = __uint_as_float(in.u[p] & 0xFFFF0000u);
        lo = fmaxf(fmaf(lo, scp[2 * p], shp[2 * p]), 0.f);
        hi = fmaxf(fmaf(hi, scp[2 * p + 1], shp[2 * p + 1]), 0.f);
        asm("v_cvt_pk_bf16_f32 %0, %1, %2" : "=v"(out.u[p]) : "v"(lo), "v"(hi));
    }
    return out.v;
}

// ---------------- CSR build ----------------

__global__ void k_count(const int* __restrict__ dst, int* __restrict__ deg) {
    int e = blockIdx.x * blockDim.x + threadIdx.x;
    if (e < NE) atomicAdd(&deg[dst[e]], 1);
}

__global__ __launch_bounds__(256) void k_scan1(const int* __restrict__ deg,
                                               int* __restrict__ part,
                                               int* __restrict__ btot) {
    __shared__ int sd[256];
    int t = threadIdx.x;
    int i = blockIdx.x * 256 + t;
    int v = (i < NN) ? deg[i] : 0;
    sd[t] = v;
    __syncthreads();
#pragma unroll
    for (int off = 1; off < 256; off <<= 1) {
        int x = (t >= off) ? sd[t - off] : 0;
        __syncthreads();
        sd[t] += x;
        __syncthreads();
    }
    if (i < NN) part[i] = sd[t];
    if (t == 255) btot[blockIdx.x] = sd[255];
}

// scan3: own prefix over raw btot + rowp/cur + graph counts (scan2 eliminated)
__global__ __launch_bounds__(256) void k_scan3(const int* __restrict__ part,
                                               const int* __restrict__ btot,
                                               const int* __restrict__ deg,
                                               int* __restrict__ rowp,
                                               int* __restrict__ cur,
                                               const int* __restrict__ batch,
                                               int* __restrict__ cnt) {
    __shared__ int hh[NG];
    __shared__ int ws4[4];
    int t = threadIdx.x;
    int i = blockIdx.x * 256 + t;
    // base = sum of raw block totals before this block
    int partial = 0;
    for (int j = t; j < (int)blockIdx.x; j += 256) partial += btot[j];
#pragma unroll
    for (int o = 32; o; o >>= 1) partial += __shfl_xor(partial, o);
    if ((t & 63) == 0) ws4[t >> 6] = partial;
    for (int j = t; j < NG; j += 256) hh[j] = 0;
    __syncthreads();
    int base = ws4[0] + ws4[1] + ws4[2] + ws4[3];
    if (i < NN) {
        int s = part[i] + base;
        rowp[i + 1] = s;
        cur[i] = s - deg[i];
        atomicAdd(&hh[batch[i]], 1);
    }
    if (i == 0) rowp[0] = 0;
    __syncthreads();
    for (int j = t; j < NG; j += 256)
        if (hh[j]) atomicAdd(&cnt[j], hh[j]);
}

__global__ void k_scatter(const int* __restrict__ src, const int* __restrict__ dst,
                          int* __restrict__ cur, int* __restrict__ csrc) {
    int e = blockIdx.x * blockDim.x + threadIdx.x;
    if (e < NE) {
        int d = dst[e];
        int p = atomicAdd(&cur[d], 1);
        csrc[p] = src[e];
    }
}

// ---------------- unified weight prep: cvt x3 | merge x2 | bias x2 (flat grid) ----------------

__global__ __launch_bounds__(256) void k_wprep(const float* __restrict__ c0_w2,
                                               const float* __restrict__ cw2,
                                               const float* __restrict__ cw1,
                                               const float* __restrict__ c0_w3,
                                               const float* __restrict__ cw3,
                                               const float* __restrict__ c0_b3,
                                               const float* __restrict__ cb3,
                                               u16* __restrict__ wpad,
                                               float* __restrict__ bb1,
                                               float* __restrict__ bb2) {
    const int b = blockIdx.x;
    const int t = threadIdx.x;
    if (b < 244) {
        int i = b * 256 + t;   // over 3*400*52
        if (i >= 3 * 400 * 52) return;
        int rc = i / 52;
        int c8 = (i % 52) * 8;
        u16x8 o = {0, 0, 0, 0, 0, 0, 0, 0};
        if (c8 < 400) {
            int mat = rc / 400, row = rc % 400;
            const float* s = (mat == 0 ? c0_w2 : mat == 1 ? cw2 : cw2 + 160000)
                             + (long)row * 400;
            float4 a = *(const float4*)(s + c8);
            float4 bb = *(const float4*)(s + c8 + 4);
            o[0] = f2bf(a.x); o[1] = f2bf(a.y); o[2] = f2bf(a.z); o[3] = f2bf(a.w);
            o[4] = f2bf(bb.x); o[5] = f2bf(bb.y); o[6] = f2bf(bb.z); o[7] = f2bf(bb.w);
        }
        *(u16x8*)(wpad + (long)rc * KP + c8) = o;
    } else if (b < 342) {
        __shared__ float As[16][68];
        __shared__ float Bs[16][68];
        const int b2 = (b < 293) ? b - 244 : b - 293;
        const float* Wa = (b < 293) ? cw1 : cw1 + 160000;
        const float* Wb = (b < 293) ? c0_w3 : cw3;
        u16* dst = wpad + (size_t)((b < 293) ? 3 : 4) * 400 * KP;
        const int bc = (b2 / 7) * 64, bj = (b2 % 7) * 64;
        const int tx = t & 15, ty = t >> 4;
        float acc[4][4] = {};
        for (int k0 = 0; k0 < 400; k0 += 16) {
            {
                int c = bc + (t >> 2);
                int kq = (t & 3) * 4;
                float4 v = make_float4(0.f, 0.f, 0.f, 0.f);
                if (c < 400) v = *(const float4*)(Wa + (long)c * 400 + k0 + kq);
                As[kq + 0][t >> 2] = v.x; As[kq + 1][t >> 2] = v.y;
                As[kq + 2][t >> 2] = v.z; As[kq + 3][t >> 2] = v.w;
            }
            {
                int k = k0 + (t >> 4);
                int jq = (t & 15) * 4;
                int j = bj + jq;
                float4 v = make_float4(0.f, 0.f, 0.f, 0.f);
                if (j < 400) v = *(const float4*)(Wb + (long)k * 400 + j);
                Bs[t >> 4][jq + 0] = v.x; Bs[t >> 4][jq + 1] = v.y;
                Bs[t >> 4][jq + 2] = v.z; Bs[t >> 4][jq + 3] = v.w;
            }
            __syncthreads();
#pragma unroll
            for (int kk = 0; kk < 16; ++kk) {
                float4 av = *(const float4*)&As[kk][ty * 4];
                float4 bv = *(const float4*)&Bs[kk][tx * 4];
                float a[4] = {av.x, av.y, av.z, av.w};
                float bb[4] = {bv.x, bv.y, bv.z, bv.w};
#pragma unroll
                for (int i = 0; i < 4; ++i)
#pragma unroll
                    for (int j = 0; j < 4; ++j)
                        acc[i][j] = fmaf(a[i], bb[j], acc[i][j]);
            }
            __syncthreads();
        }
#pragma unroll
        for (int i = 0; i < 4; ++i) {
            int c = bc + ty * 4 + i;
            if (c >= 400) continue;
#pragma unroll
            for (int j = 0; j < 4; ++j) {
                int col = bj + tx * 4 + j;
                if (col < KP) dst[(long)c * KP + col] = (col < 400) ? f2bf(acc[i][j]) : 0;
            }
        }
    } else {
        const int c = (b & 1) * 256 + t;
        if (c >= 400) return;
        const float* Wa = (b < 344) ? cw1 : cw1 + 160000;
        const float* bv = (b < 344) ? c0_b3 : cb3;
        float* out = (b < 344) ? bb1 : bb2;
        const float4* wr = (const float4*)(Wa + (long)c * 400);
        const float4* br = (const float4*)bv;
        float s0 = 0.f, s1 = 0.f, s2 = 0.f, s3 = 0.f;
        for (int q = 0; q < 100; ++q) {
            float4 a = wr[q], v = br[q];
            s0 = fmaf(a.x, v.x, s0); s1 = fmaf(a.y, v.y, s1);
            s2 = fmaf(a.z, v.z, s2); s3 = fmaf(a.w, v.w, s3);
        }
        out[c] = s0 + s1 + s2 + s3;
    }
}

// ---------------- agg0 + moments ----------------

__global__ __launch_bounds__(256) void k_agg0(const float* __restrict__ x,
                                              const int* __restrict__ rowp,
                                              const int* __restrict__ csrc,
                                              float* __restrict__ out,
                                              float* __restrict__ mom) {
    __shared__ float ws[4][14];
    int n = blockIdx.x * blockDim.x + threadIdx.x;
    float4 acc = make_float4(0.f, 0.f, 0.f, 0.f);
    if (n < NN) {
        int b = rowp[n], e = rowp[n + 1];
        for (int p = b; p < e; ++p) {
            float4 v = ((const float4*)x)[csrc[p]];
            acc.x += v.x; acc.y += v.y; acc.z += v.z; acc.w += v.w;
        }
        ((float4*)out)[n] = acc;
    }
    float mv[14] = {acc.x, acc.y, acc.z, acc.w,
                    acc.x * acc.x, acc.x * acc.y, acc.x * acc.z, acc.x * acc.w,
                    acc.y * acc.y, acc.y * acc.z, acc.y * acc.w,
                    acc.z * acc.z, acc.z * acc.w, acc.w * acc.w};
    int wv = threadIdx.x >> 6, l = threadIdx.x & 63;
#pragma unroll
    for (int i = 0; i < 14; ++i) {
        float s = mv[i];
#pragma unroll
        for (int o = 32; o; o >>= 1) s += __shfl_xor(s, o);
        if (l == 0) ws[wv][i] = s;
    }
    __syncthreads();
    if (threadIdx.x < 14) {
        float s = ws[0][threadIdx.x] + ws[1][threadIdx.x] + ws[2][threadIdx.x] + ws[3][threadIdx.x];
        atomicAdd(&mom[threadIdx.x], s);
    }
}

// ---------------- aggH: one wave per node (latency-optimal) ----------------

__global__ __launch_bounds__(256) void k_aggH(const u16* __restrict__ h,
                                              const int* __restrict__ rowp,
                                              const int* __restrict__ csrc,
                                              const float* __restrict__ bias,
                                              u16* __restrict__ out) {
    int n = (blockIdx.x << 2) + (threadIdx.x >> 6);
    if (n >= NN) return;
    int l = threadIdx.x & 63;
    if (l >= 50) return;
    float4 b0 = *(const float4*)(bias + l * 8);
    float4 b1 = *(const float4*)(bias + l * 8 + 4);
    float acc[8] = {b0.x, b0.y, b0.z, b0.w, b1.x, b1.y, b1.z, b1.w};
    int b = rowp[n], e = rowp[n + 1];
    for (int p = b; p < e; ++p) {
        const u16* r = h + (long)csrc[p] * H + l * 8;
        u16x8 v = *(const u16x8*)r;
#pragma unroll
        for (int q = 0; q < 8; ++q) acc[q] += bf2f(v[q]);
    }
    u16x8 o;
#pragma unroll
    for (int q = 0; q < 8; ++q) o[q] = f2bf(acc[q]);
    *(u16x8*)(out + (long)n * H + l * 8) = o;
}

// ---------------- first linear (K = 4) + fused analytic z1 stats ----------------

static constexpr int NLIN0 = (int)(((long)NN * 100 + 255) / 256);

__global__ void k_lin0(const float* __restrict__ a4, const float* __restrict__ w,
                       const float* __restrict__ b, u16* __restrict__ out,
                       const float* __restrict__ mom, float* __restrict__ slot0) {
    if (blockIdx.x >= NLIN0) {
        int j = (blockIdx.x - NLIN0) * 256 + threadIdx.x;
        if (j >= 400) return;
        float4 wv = ((const float4*)w)[j];
        float dot = wv.x * mom[0] + wv.y * mom[1] + wv.z * mom[2] + wv.w * mom[3];
        float quad = wv.x * wv.x * mom[4] + 2.f * wv.x * wv.y * mom[5]
                   + 2.f * wv.x * wv.z * mom[6] + 2.f * wv.x * wv.w * mom[7]
                   + wv.y * wv.y * mom[8] + 2.f * wv.y * wv.z * mom[9]
                   + 2.f * wv.y * wv.w * mom[10] + wv.z * wv.z * mom[11]
                   + 2.f * wv.z * wv.w * mom[12] + wv.w * wv.w * mom[13];
        float bj = b[j];
        slot0[j] = dot + (float)NN * bj;
        slot0[KP + j] = quad + 2.f * bj * dot + (float)NN * bj * bj;
        return;
    }
    long i = (long)blockIdx.x * blockDim.x + threadIdx.x;
    if (i >= (long)NN * 100) return;
    int n = (int)(i / 100), q = (int)(i - (long)n * 100);
    int j0 = q * 4;
    float4 av = ((const float4*)a4)[n];
    u16x4 o;
#pragma unroll
    for (int jj = 0; jj < 4; ++jj) {
        float4 wv = ((const float4*)w)[j0 + jj];
        float s = fmaf(av.x, wv.x, fmaf(av.y, wv.y, fmaf(av.z, wv.z, av.w * wv.w)));
        o[jj] = f2bf(s + b[j0 + jj]);
    }
    *(u16x4*)(out + (long)n * H + j0) = o;
}

// ---------------- BN stats over bf16 buffer -> replica slot ----------------

__global__ __launch_bounds__(256) void k_statsv(const u16* __restrict__ z,
                                                float* __restrict__ stats) {
    __shared__ float ls[800];
    int t = threadIdx.x;
    for (int i = t; i < 800; i += 256) ls[i] = 0.f;
    __syncthreads();
    if (t < 250) {
        int sub = t / 50, seg = t % 50;
        float s[8] = {0, 0, 0, 0, 0, 0, 0, 0};
        float q[8] = {0, 0, 0, 0, 0, 0, 0, 0};
        for (int r = blockIdx.x * 5 + sub; r < NN; r += gridDim.x * 5) {
            u16x8 v = *(const u16x8*)(z + (long)r * H + seg * 8);
#pragma unroll
            for (int j = 0; j < 8; ++j) {
                float f = bf2f(v[j]);
                s[j] += f; q[j] += f * f;
            }
        }
#pragma unroll
        for (int j = 0; j < 8; ++j) {
            atomicAdd(&ls[seg * 8 + j], s[j]);
            atomicAdd(&ls[400 + seg * 8 + j], q[j]);
        }
    }
    __syncthreads();
    const int rep = blockIdx.x & (SREP - 1);
    for (int i = t; i < 800; i += 256) {
        int col = (i < 400) ? i : (i - 400 + KP);
        atomicAdd(&stats[rep * 2 * KP + col], ls[i]);
    }
}

// ---------------- MFMA GEMM (R17 structure) + optional fused poolf blocks (FIRST) ----------------
// POOL: blocks [0, PBLK) run the pooled-f2 reduction over A (same input, same BN
// stats) -> pf; scheduled FIRST so they overlap the GEMM ramp (L2-warm A reads).
// GEMM blocks are the remaining NWGG.

template <bool STATS, bool POOL>
__global__ __launch_bounds__(256) void gemm_mfma(const u16* __restrict__ A,
                                                 const u16* __restrict__ Wp,
                                                 const float* __restrict__ bias,
                                                 const float* __restrict__ bnG,
                                                 const float* __restrict__ bnBe,
                                                 const float* __restrict__ statsIn,
                                                 float* __restrict__ statsOut,
                                                 u16* __restrict__ out,
                                                 const int* __restrict__ batch,
                                                 float* __restrict__ pf, int M) {
    constexpr int BUF = 6656;            // u16 per buffer: A 4096 + B 2560
    __shared__ u16 lds[3 * BUF];         // 39,936 B
    __shared__ float sdScale[KP];
    __shared__ float sdShift[KP];
    __shared__ float sst[160];

    const int t = threadIdx.x;

    if (POOL && blockIdx.x < PBLK) {
        // ---- fused poolf block (runs first, overlaps GEMM ramp) ----
        const int pb = blockIdx.x;
        for (int j = t; j < 400; j += 256) {
            float s = 0.f, q = 0.f;
#pragma unroll
            for (int r = 0; r < SREP; ++r) {
                s += statsIn[r * 2 * KP + j];
                q += statsIn[r * 2 * KP + KP + j];
            }
            float m = s / NN, v = fmaxf(q / NN - m * m, 0.f);
            float rs = rsqrtf(v + EPS);
            float sc = bnG[j] * rs;
            sdScale[j] = sc;
            sdShift[j] = bnBe[j] - m * sc;
        }
        __syncthreads();
        if (t >= 250) return;
        const int sub = t / 50, seg = t % 50;
        float sc[8], sh[8];
#pragma unroll
        for (int q = 0; q < 8; ++q) {
            sc[q] = sdScale[seg * 8 + q];
            sh[q] = sdShift[seg * 8 + q];
        }
        int rows = (NN + PBLK - 1) / PBLK;
        int r0 = pb * rows;
        int r1 = min(r0 + rows, NN);
        float acc[8] = {0.f, 0.f, 0.f, 0.f, 0.f, 0.f, 0.f, 0.f};
        int gp = -1;
        for (int r = r0 + sub; r < r1; r += 5) {
            int gg = batch[r];
            if (gg != gp) {
                if (gp >= 0) {
#pragma unroll
                    for (int q = 0; q < 8; ++q)
                        atomicAdd(&pf[(long)gp * 400 + seg * 8 + q], acc[q]);
                }
#pragma unroll
                for (int q = 0; q < 8; ++q) acc[q] = 0.f;
                gp = gg;
            }
            u16x8 v = *(const u16x8*)(A + (long)r * H + seg * 8);
#pragma unroll
            for (int q = 0; q < 8; ++q)
                acc[q] += fmaxf(fmaf(bf2f(v[q]), sc[q], sh[q]), 0.f);
        }
        if (gp >= 0) {
#pragma unroll
            for (int q = 0; q < 8; ++q)
                atomicAdd(&pf[(long)gp * 400 + seg * 8 + q], acc[q]);
        }
        return;
    }

    const int gb = POOL ? (int)blockIdx.x - PBLK : (int)blockIdx.x;
    // bijective XCD swizzle over the NWGG gemm blocks (1955, not divisible by 8)
    const int q8 = NWGG >> 3, r8 = NWGG & 7;
    const int xcd = gb & 7, jj = gb >> 3;
    const int wgid = (xcd < r8 ? xcd * (q8 + 1) : r8 * (q8 + 1) + (xcd - r8) * q8) + jj;
    const int bm = (wgid / 5) * 128;
    const int bn = (wgid % 5) * 80;
    const int w = t >> 6, l = t & 63;

    // ---- BN finalize prologue ----
    for (int j = t; j < KP; j += 256) {
        float s = 0.f, q = 0.f;
#pragma unroll
        for (int r = 0; r < SREP; ++r) {
            s += statsIn[r * 2 * KP + j];
            q += statsIn[r * 2 * KP + KP + j];
        }
        float sc = 0.f, sh = 0.f;
        if (j < H) {
            float m = s / NN;
            float v = fmaxf(q / NN - m * m, 0.f);
            float rs = rsqrtf(v + EPS);
            sc = bnG[j] * rs;
            sh = bnBe[j] - m * sc;
        }
        sdScale[j] = sc;
        sdShift[j] = sh;
    }

    const int srow = l >> 2;
    const int sck  = ((l & 3) ^ ((l >> 3) & 3)) * 8;   // source-side XOR swizzle

    auto stageTile = [&](int b, int kt) {
        u16* dst = lds + b * BUF;
        const int k0 = kt * 32;
        long g0 = (long)bm + w * 16 + srow;
        long g1 = g0 + 64;
        if (g0 > M - 1) g0 = M - 1;
        if (g1 > M - 1) g1 = M - 1;
        gload_lds16(A + g0 * 400 + k0 + sck, dst + w * 512);
        gload_lds16(A + g1 * 400 + k0 + sck, dst + (w + 4) * 512);
        gload_lds16(Wp + (long)(bn + w * 16 + srow) * KP + k0 + sck,
                    dst + 4096 + w * 512);
        gload_lds16(Wp + (long)(bn + 64 + srow) * KP + k0 + sck,
                    dst + 4096 + 4 * 512);       // B seg 4 (x4 dup -> uniform 4 loads/wave)
    };

    f32x4 acc[2][5];
#pragma unroll
    for (int i = 0; i < 2; ++i)
#pragma unroll
        for (int c = 0; c < 5; ++c)
            acc[i][c] = (f32x4){0.f, 0.f, 0.f, 0.f};

    const int r16 = l & 15;
    const int cc  = l >> 4;
    const int swz = r16 * 32 + (((cc ^ ((r16 >> 1) & 3))) << 3);

    auto computeTile = [&](int b, int s) {
        const u16* base = lds + b * BUF;
        const u16* ab = base + w * 1024 + swz;
        const u16* bb = base + 4096 + swz;
        bf16x8 fa0 = *(const bf16x8*)ab;
        bf16x8 fa1 = *(const bf16x8*)(ab + 512);
        const int k = s * 32 + cc * 8;
        fa0 = bnrelu8(fa0, sdScale + k, sdShift + k);
        fa1 = bnrelu8(fa1, sdScale + k, sdShift + k);
        __builtin_amdgcn_s_setprio(1);
#pragma unroll
        for (int c = 0; c < 5; ++c) {
            bf16x8 fb = *(const bf16x8*)(bb + c * 512);
            acc[0][c] = __builtin_amdgcn_mfma_f32_16x16x32_bf16(fa0, fb, acc[0][c], 0, 0, 0);
            acc[1][c] = __builtin_amdgcn_mfma_f32_16x16x32_bf16(fa1, fb, acc[1][c], 0, 0, 0);
        }
        __builtin_amdgcn_s_setprio(0);
    };

    // prologue: tiles 0,1 in flight (8 loads/wave)
    stageTile(0, 0);
    stageTile(1, 1);

#pragma unroll 1
    for (int s = 0; s < 12; ++s) {
        asm volatile("s_waitcnt vmcnt(4)" ::: "memory");
        __builtin_amdgcn_s_barrier();
        if (s + 2 < 13) stageTile((s + 2) % 3, s + 2);
        computeTile(s % 3, s);
    }
    asm volatile("s_waitcnt vmcnt(0)" ::: "memory");
    __builtin_amdgcn_s_barrier();
    computeTile(12 % 3, 12);

    // ---- epilogue: LDS-bounced coalesced stores + fused stats ----
    u16* tile = lds;
    __syncthreads();
    if (STATS) for (int i = t; i < 160; i += 256) sst[i] = 0.f;
    if (STATS) __syncthreads();

    float ssum[5], sqq[5];
#pragma unroll
    for (int c = 0; c < 5; ++c) { ssum[c] = 0.f; sqq[c] = 0.f; }
#pragma unroll
    for (int i = 0; i < 2; ++i) {
        const int lrow0 = w * 32 + i * 16 + (l >> 4) * 4;
#pragma unroll
        for (int c = 0; c < 5; ++c) {
            const int lcol = c * 16 + (l & 15);
            const float bv = bias[bn + lcol];
#pragma unroll
            for (int r = 0; r < 4; ++r) {
                const int lrow = lrow0 + r;
                float z = acc[i][c][r] + bv;
                tile[lrow * 80 + lcol] = f2bf(z);
                if (STATS && bm + lrow < M) { ssum[c] += z; sqq[c] += z * z; }
            }
        }
    }
    __syncthreads();
#pragma unroll
    for (int j = 0; j < 5; ++j) {
        int chunk = t + j * 256;
        int row = chunk / 10, c8 = chunk % 10;
        if (bm + row < M) {
            u16x8 v = *(const u16x8*)(tile + row * 80 + c8 * 8);
            *(u16x8*)(out + (long)(bm + row) * H + bn + c8 * 8) = v;
        }
    }
    if (STATS) {
        const int rep = wgid & (SREP - 1);
#pragma unroll
        for (int c = 0; c < 5; ++c) {
            ssum[c] += __shfl_xor(ssum[c], 16); ssum[c] += __shfl_xor(ssum[c], 32);
            sqq[c]  += __shfl_xor(sqq[c], 16);  sqq[c]  += __shfl_xor(sqq[c], 32);
        }
        if (l < 16) {
#pragma unroll
            for (int c = 0; c < 5; ++c) {
                atomicAdd(&sst[c * 16 + l], ssum[c]);
                atomicAdd(&sst[80 + c * 16 + l], sqq[c]);
            }
        }
        __syncthreads();
        if (t < 80)       atomicAdd(&statsOut[rep * 2 * KP + bn + t], sst[t]);
        else if (t < 160) atomicAdd(&statsOut[rep * 2 * KP + KP + bn + (t - 80)], sst[t]);
    }
}

// ---------------- standalone poolf (layer 2 only) ----------------

__global__ __launch_bounds__(256) void k_poolf(const u16* __restrict__ z,
                                               const float* __restrict__ statsIn,
                                               const float* __restrict__ gw,
                                               const float* __restrict__ be,
                                               const int* __restrict__ batch,
                                               float* __restrict__ pf) {
    __shared__ float sdS[400];
    __shared__ float sdH[400];
    int t = threadIdx.x;
    for (int j = t; j < 400; j += 256) {
        float s = 0.f, q = 0.f;
#pragma unroll
        for (int r = 0; r < SREP; ++r) {
            s += statsIn[r * 2 * KP + j];
            q += statsIn[r * 2 * KP + KP + j];
        }
        float m = s / NN, v = fmaxf(q / NN - m * m, 0.f);
        float rs = rsqrtf(v + EPS);
        float sc = gw[j] * rs;
        sdS[j] = sc;
        sdH[j] = be[j] - m * sc;
    }
    __syncthreads();
    if (t >= 250) return;
    const int sub = t / 50, seg = t % 50;
    float sc[8], sh[8];
#pragma unroll
    for (int q = 0; q < 8; ++q) {
        sc[q] = sdS[seg * 8 + q];
        sh[q] = sdH[seg * 8 + q];
    }
    int rows = (NN + gridDim.x - 1) / gridDim.x;
    int r0 = blockIdx.x * rows;
    int r1 = min(r0 + rows, NN);
    float acc[8] = {0.f, 0.f, 0.f, 0.f, 0.f, 0.f, 0.f, 0.f};
    int gp = -1;
    for (int r = r0 + sub; r < r1; r += 5) {
        int gg = batch[r];
        if (gg != gp) {
            if (gp >= 0) {
#pragma unroll
                for (int q = 0; q < 8; ++q)
                    atomicAdd(&pf[(long)gp * 400 + seg * 8 + q], acc[q]);
            }
#pragma unroll
            for (int q = 0; q < 8; ++q) acc[q] = 0.f;
            gp = gg;
        }
        u16x8 v = *(const u16x8*)(z + (long)r * H + seg * 8);
#pragma unroll
        for (int q = 0; q < 8; ++q)
            acc[q] += fmaxf(fmaf(bf2f(v[q]), sc[q], sh[q]), 0.f);
    }
    if (gp >= 0) {
#pragma unroll
        for (int q = 0; q < 8; ++q)
            atomicAdd(&pf[(long)gp * 400 + seg * 8 + q], acc[q]);
    }
}

// ---------------- pools[g][L*400+c] = pf[L][g]·W3_L[c]ᵀ + cnt[g]*b3_L[c] ----------------

__global__ __launch_bounds__(256) void k_poolgemm(const float* __restrict__ pf,
                                                  const float* __restrict__ w30,
                                                  const float* __restrict__ w312,
                                                  const float* __restrict__ b30,
                                                  const float* __restrict__ b312,
                                                  const int* __restrict__ cnt,
                                                  float* __restrict__ pools) {
    __shared__ __align__(16) float xr[400];
    int g = blockIdx.x, L = blockIdx.y, t = threadIdx.x;
    const float* w = (L == 0) ? w30 : w312 + (size_t)(L - 1) * 400 * 400;
    const float* b = (L == 0) ? b30 : b312 + (L - 1) * 400;
    for (int i = t; i < 400; i += 256) xr[i] = pf[((long)L * NG + g) * 400 + i];
    __syncthreads();
    float cg = (float)cnt[g];
    for (int c = t; c < 400; c += 256) {
        const float4* wr = (const float4*)(w + (long)c * 400);
        const float4* xv = (const float4*)xr;
        float s0 = 0.f, s1 = 0.f, s2 = 0.f, s3 = 0.f;
        for (int q = 0; q < 100; ++q) {
            float4 a = xv[q], bb = wr[q];
            s0 = fmaf(a.x, bb.x, s0); s1 = fmaf(a.y, bb.y, s1);
            s2 = fmaf(a.z, bb.z, s2); s3 = fmaf(a.w, bb.w, s3);
        }
        pools[(long)g * 1200 + L * 400 + c] = s0 + s1 + s2 + s3 + cg * b[c];
    }
}

// ---------------- readout ----------------

__global__ __launch_bounds__(256) void k_lin1(const float* __restrict__ pools,
                                              const float* __restrict__ w1,
                                              const float* __restrict__ b1,
                                              float* __restrict__ zz) {
    __shared__ __align__(16) float xg[8][1200];
    const int bandj = blockIdx.x * 40;
    const int g0 = blockIdx.y * 8;
    const int t = threadIdx.x;
    for (int i = t; i < 9600; i += 256)
        xg[i / 1200][i % 1200] = pools[(long)(g0 + i / 1200) * 1200 + (i % 1200)];
    __syncthreads();
    const int wv = t >> 6, l = t & 63;
    for (int jj = wv; jj < 40; jj += 4) {
        const int j = bandj + jj;
        const float4* wr = (const float4*)(w1 + (long)j * 1200);
        float s[8] = {0.f, 0.f, 0.f, 0.f, 0.f, 0.f, 0.f, 0.f};
        for (int q = l; q < 300; q += 64) {
            float4 wq = wr[q];
#pragma unroll
            for (int g = 0; g < 8; ++g) {
                float4 xv = *(const float4*)&xg[g][q * 4];
                s[g] = fmaf(wq.x, xv.x, s[g]);
                s[g] = fmaf(wq.y, xv.y, s[g]);
                s[g] = fmaf(wq.z, xv.z, s[g]);
                s[g] = fmaf(wq.w, xv.w, s[g]);
            }
        }
#pragma unroll
        for (int g = 0; g < 8; ++g)
#pragma unroll
            for (int o = 32; o; o >>= 1) s[g] += __shfl_xor(s[g], o);
        if (l == 0) {
            const float bj = b1[j];
#pragma unroll
            for (int g = 0; g < 8; ++g)
                zz[(long)(g0 + g) * 600 + j] = fmaxf(s[g] + bj, 0.f);
        }
    }
}

__global__ __launch_bounds__(64) void k_lin2(const float* __restrict__ zz,
                                             const float* __restrict__ w2,
                                             const float* __restrict__ b2,
                                             float* __restrict__ out) {
    int g = blockIdx.x;
    int l = threadIdx.x;
    float p[NC];
#pragma unroll
    for (int c = 0; c < NC; ++c) p[c] = 0.f;
    for (int k = l; k < 600; k += 64) {
        float zv = zz[(long)g * 600 + k];
#pragma unroll
        for (int c = 0; c < NC; ++c) p[c] = fmaf(zv, w2[c * 600 + k], p[c]);
    }
#pragma unroll
    for (int c = 0; c < NC; ++c)
#pragma unroll
        for (int o = 32; o; o >>= 1) p[c] += __shfl_xor(p[c], o);
    if (l == 0) {
        float lg[NC];
        float mx = -1e30f;
#pragma unroll
        for (int c = 0; c < NC; ++c) { lg[c] = p[c] + b2[c]; mx = fmaxf(mx, lg[c]); }
        float se = 0.f;
#pragma unroll
        for (int c = 0; c < NC; ++c) se += expf(lg[c] - mx);
        float lse = logf(se);
#pragma unroll
        for (int c = 0; c < NC; ++c) out[(long)g * NC + c] = lg[c] - mx - lse;
    }
}

// ---------------- launch ----------------

extern "C" void kernel_launch(void* const* d_in, const int* in_sizes, int n_in,
                              void* d_out, int out_size, void* d_ws, size_t ws_size,
                              hipStream_t stream) {
    const float* x      = (const float*)d_in[0];
    const int*   ei     = (const int*)d_in[1];
    const int*   batch  = (const int*)d_in[2];
    const float* c0_w1  = (const float*)d_in[4];
    const float* c0_b1  = (const float*)d_in[5];
    const float* c0_g1  = (const float*)d_in[6];
    const float* c0_be1 = (const float*)d_in[7];
    const float* c0_w2  = (const float*)d_in[8];
    const float* c0_b2  = (const float*)d_in[9];
    const float* c0_g2  = (const float*)d_in[10];
    const float* c0_be2 = (const float*)d_in[11];
    const float* c0_w3  = (const float*)d_in[12];
    const float* c0_b3  = (const float*)d_in[13];
    const float* cw1    = (const float*)d_in[14];
    const float* cb1    = (const float*)d_in[15];
    const float* cg1    = (const float*)d_in[16];
    const float* cbe1   = (const float*)d_in[17];
    const float* cw2    = (const float*)d_in[18];
    const float* cb2    = (const float*)d_in[19];
    const float* cg2    = (const float*)d_in[20];
    const float* cbe2   = (const float*)d_in[21];
    const float* cw3    = (const float*)d_in[22];
    const float* cb3    = (const float*)d_in[23];
    const float* lin1_w = (const float*)d_in[24];
    const float* lin1_b = (const float*)d_in[25];
    const float* lin2_w = (const float*)d_in[26];
    const float* lin2_b = (const float*)d_in[27];

    const int* src = ei;
    const int* dst = ei + NE;

    char* ws = (char*)d_ws;
    size_t off = 0;
    auto alloc = [&](size_t bytes) {
        void* p = ws + off;
        off += (bytes + 255) & ~(size_t)255;
        return p;
    };
    u16*   bufh   = (u16*)alloc((size_t)NN * H * 2 + 128);   // K-tail overread pad
    u16*   bufa   = (u16*)alloc((size_t)NN * H * 2 + 128);
    float* agg0   = (float*)alloc((size_t)NN * 4 * 4);
    // ---- contiguous zero region: deg | statsA | mom | pf | cnt ----
    char*  zstart = ws + off;
    int*   deg    = (int*)alloc((size_t)NN * 4);
    float* statsA = (float*)alloc((size_t)6 * SSLOT * 4);
    float* mom    = (float*)alloc(14 * 4);
    float* pf     = (float*)alloc((size_t)3 * NG * 400 * 4);
    int*   cnt    = (int*)alloc((size_t)NG * 4);
    size_t zbytes = (size_t)((ws + off) - zstart);
    // ---- rest ----
    float* pools  = (float*)alloc((size_t)NG * 3 * H * 4);
    float* zz     = (float*)alloc((size_t)NG * 600 * 4);
    float* bb1    = (float*)alloc(400 * 4);
    float* bb2    = (float*)alloc(400 * 4);
    u16*   wpad   = (u16*)alloc((size_t)5 * 400 * KP * 2);
    int*   rowp   = (int*)alloc((size_t)(NN + 1) * 4);
    int*   cur    = (int*)alloc((size_t)NN * 4);
    int*   csrc   = (int*)alloc((size_t)NE * 4);
    int*   part   = (int*)alloc((size_t)NN * 4);
    int*   btot   = (int*)alloc((size_t)NB1 * 4);

    auto wp   = [&](int mat) { return wpad + (size_t)mat * 400 * KP; };
    auto slot = [&](int i)   { return statsA + (size_t)i * SSLOT; };

    hipMemsetAsync(zstart, 0, zbytes, stream);

    k_wprep<<<346, 256, 0, stream>>>(c0_w2, cw2, cw1, c0_w3, cw3, c0_b3, cb3,
                                     wpad, bb1, bb2);

    // CSR build + graph counts (scan2 folded into scan3)
    k_count<<<(NE + 255) / 256, 256, 0, stream>>>(dst, deg);
    k_scan1<<<NB1, 256, 0, stream>>>(deg, part, btot);
    k_scan3<<<NB1, 256, 0, stream>>>(part, btot, deg, rowp, cur, batch, cnt);
    k_scatter<<<(NE + 255) / 256, 256, 0, stream>>>(src, dst, cur, csrc);

    // layer 0: agg0(+moments) -> lin0(+analytic stats); z2 -> y2(+fused pool L0)
    k_agg0<<<NB1, 256, 0, stream>>>(x, rowp, csrc, agg0, mom);
    k_lin0<<<NLIN0 + 2, 256, 0, stream>>>(agg0, c0_w1, c0_b1, bufh, mom, slot(0));
    gemm_mfma<true, false><<<NWGG, 256, 0, stream>>>(
        bufh, wp(0), c0_b2, c0_g1, c0_be1, slot(0), slot(1), bufa, nullptr, nullptr, NN);
    gemm_mfma<false, true><<<NWGG + PBLK, 256, 0, stream>>>(
        bufa, wp(3), bb1, c0_g2, c0_be2, slot(1), nullptr, bufh, batch, pf, NN);

    // layer 1
    k_aggH<<<(NN + 3) / 4, 256, 0, stream>>>(bufh, rowp, csrc, cb1, bufa);          // z1'
    k_statsv<<<512, 256, 0, stream>>>(bufa, slot(2));
    gemm_mfma<true, false><<<NWGG, 256, 0, stream>>>(
        bufa, wp(1), cb2, cg1, cbe1, slot(2), slot(3), bufh, nullptr, nullptr, NN);  // z2'
    gemm_mfma<false, true><<<NWGG + PBLK, 256, 0, stream>>>(
        bufh, wp(4), bb2, cg2, cbe2, slot(3), nullptr, bufa, batch,
        pf + (size_t)NG * 400, NN);                                                  // y2' + pool L1

    // layer 2
    k_aggH<<<(NN + 3) / 4, 256, 0, stream>>>(bufa, rowp, csrc, cb1 + 400, bufh);    // z1''
    k_statsv<<<512, 256, 0, stream>>>(bufh, slot(4));
    gemm_mfma<true, false><<<NWGG, 256, 0, stream>>>(
        bufh, wp(2), cb2 + 400, cg1 + 400, cbe1 + 400, slot(4), slot(5), bufa,
        nullptr, nullptr, NN);                                                       // z2''
    k_poolf<<<512, 256, 0, stream>>>(bufa, slot(5), cg2 + 400, cbe2 + 400, batch,
                                     pf + (size_t)2 * NG * 400);

    // pools = pf * W3^T + cnt*b3, then readout
    dim3 gp(NG, 3);
    k_poolgemm<<<gp, 256, 0, stream>>>(pf, c0_w3, cw3, c0_b3, cb3, cnt, pools);
    dim3 gl1(15, 16);
    k_lin1<<<gl1, 256, 0, stream>>>(pools, lin1_w, lin1_b, zz);
    k_lin2<<<NG, 64, 0, stream>>>(zz, lin2_w, lin2_b, (float*)d_out);
}